// Round 1
// baseline (315.063 us; speedup 1.0000x reference)
//
#include <hip/hip_runtime.h>
#include <hip/hip_bf16.h>

// ---------------- problem constants (fixed by setup_inputs) ----------------
#define NUM_B   16
#define DIM     512
#define TT      1500
#define NROWS   (NUM_B * TT)              // 24000
#define NCODES  4096
#define ROW_TILES ((NROWS + 127) / 128)   // 188 (fallback path)
#define NROWS_PAD (ROW_TILES * 128)       // 24064
#define NSLICE  8                         // partial cd slices (atomic decontention)
#define SHIFTC  30.0f                     // exp shift: exp(SHIFT-d), cancels in softmax
#define NBLKX   (NCODES / 128)            // 32 col tiles (fallback path)
#define TBLKS   (NUM_B * 47)              // 752 transpose blocks (47 t-tiles of 32)
#define CBLKS   (NCODES / 4)              // 1024 cb blocks
#define NZERO   (NROWS_PAD + NSLICE * NCODES)   // Sg + cdp

// 256x256 8-phase gemm1 geometry
#define NTY2 (NROWS_PAD / 256)            // 94
#define NTX2 (NCODES / 256)               // 16
#define NWG2 (NTY2 * NTX2)                // 1504 (divisible by 8 -> simple XCD swizzle)
#define KTILES (DIM / 64)                 // 8

typedef __bf16 bf16x8 __attribute__((ext_vector_type(8)));
typedef float  floatx4 __attribute__((ext_vector_type(4)));
typedef unsigned short ushortx8 __attribute__((ext_vector_type(8)));

// async global->LDS, 16B per lane; dest = wave-uniform base + lane*16
__device__ __forceinline__ void glds16(const void* g, void* l) {
    __builtin_amdgcn_global_load_lds(
        (__attribute__((address_space(1))) void*)(void*)g,
        (__attribute__((address_space(3))) void*)l, 16, 0, 0);
}

// ---------------- prep: transpose + z2 (register-accum) + cb + ws zeroing -------
__global__ __launch_bounds__(256) void k_prep(
    const float* __restrict__ sf, const float* __restrict__ cb,
    unsigned short* __restrict__ zbf, unsigned short* __restrict__ cbbf,
    float* __restrict__ z2, float* __restrict__ c2, float* __restrict__ zero0) {
    int id = blockIdx.x, tid = threadIdx.x;
    if (id < TBLKS) {
        __shared__ float tile[32][257];
        int b = id / 47, t0 = (id % 47) * 32;
        int tl = tid & 31, dg = tid >> 5;       // phase 1: t lane, d group (8x32)
        int tr = tid >> 3, dgr = tid & 7;       // phase 2: 8 lanes per t-row
        int tg = t0 + tr;
        float ssq = 0.f;
        unsigned short* dst = zbf + (size_t)(b * TT + tg) * DIM;
#pragma unroll
        for (int half = 0; half < 2; ++half) {
            int dbase = half * 256;
            if (half) __syncthreads();          // drain phase-2 reads of prev half
            int t = t0 + tl;
            if (t < TT) {
                const float* src = sf + (size_t)(b * DIM + dbase + dg * 32) * TT + t;
#pragma unroll
                for (int k = 0; k < 32; ++k)
                    tile[tl][dg * 32 + k] = src[(size_t)k * TT];
            }
            __syncthreads();
            if (tg < TT) {
#pragma unroll
                for (int seg = 0; seg < 4; ++seg) {
                    int d0 = seg * 64 + dgr * 8;
                    unsigned int h[8];
#pragma unroll
                    for (int i2 = 0; i2 < 8; ++i2) {
                        __hip_bfloat16 hb = __float2bfloat16(tile[tr][d0 + i2]);
                        h[i2] = __builtin_bit_cast(unsigned short, hb);
                        float vb = __bfloat162float(hb);
                        ssq += vb * vb;
                    }
                    uint4 o;
                    o.x = h[0] | (h[1] << 16); o.y = h[2] | (h[3] << 16);
                    o.z = h[4] | (h[5] << 16); o.w = h[6] | (h[7] << 16);
                    *(uint4*)(dst + dbase + d0) = o;
                }
            }
        }
        // reduce over the 8 lanes sharing tr (lane bits 0..2)
        ssq += __shfl_xor(ssq, 1); ssq += __shfl_xor(ssq, 2); ssq += __shfl_xor(ssq, 4);
        if (dgr == 0 && tg < TT) z2[b * TT + tg] = ssq;
    } else {
        int ci = id - TBLKS;
        int gid = ci * 256 + tid;
        if (gid < NZERO) zero0[gid] = 0.f;
        int k = ci * 4 + (tid >> 6);
        int lane = tid & 63;
        const float4* src = (const float4*)(cb + (size_t)k * DIM + lane * 8);
        float4 a = src[0], b2 = src[1];
        float vals[8] = {a.x, a.y, a.z, a.w, b2.x, b2.y, b2.z, b2.w};
        float s = 0.f;
        unsigned int h[8];
#pragma unroll
        for (int i = 0; i < 8; ++i) {
            __hip_bfloat16 hb = __float2bfloat16(vals[i]);
            h[i] = __builtin_bit_cast(unsigned short, hb);
            float vb = __bfloat162float(hb);
            s += vb * vb;
        }
        uint4 o;
        o.x = h[0] | (h[1] << 16); o.y = h[2] | (h[3] << 16);
        o.z = h[4] | (h[5] << 16); o.w = h[6] | (h[7] << 16);
        *(uint4*)(cbbf + (size_t)k * DIM + lane * 8) = o;
#pragma unroll
        for (int off = 32; off >= 1; off >>= 1) s += __shfl_down(s, off);
        if (lane == 0) c2[k] = s;
    }
}

// ---------------- pass 1: 256x256 8-phase GEMM + exp epilogue -------------------
// 8 waves (2M x 4N), BK=64, double-buffered LDS with per-phase half-tile staging
// and counted vmcnt(8) (T3+T4), read-side XOR swizzle (T2), setprio (T5).
// MFMA operands swapped (mfma(B,A,.)) so each lane's 4 acc regs = 4 consecutive
// codebook cols -> packed 8B E stores.

#define DSR(dst, addr) asm volatile("ds_read_b128 %0, %1" : "=v"(dst) : "v"(addr))
#define PIPE_SYNC() do { \
    asm volatile("s_waitcnt vmcnt(8)" ::: "memory"); \
    asm volatile("s_barrier" ::: "memory"); \
    asm volatile("s_waitcnt lgkmcnt(0)" ::: "memory"); \
    __builtin_amdgcn_sched_barrier(0); \
} while (0)
#define PIPE_POST() asm volatile("s_barrier" ::: "memory")

#define STG_A(TT_, H_) do { \
    const unsigned short* _s = agp + (size_t)(H_) * 128 * DIM + (TT_) * 64; \
    unsigned short* _d = &As[(TT_) & 1][H_][0] + (wave << 9); \
    glds16(_s, _d); glds16(_s + (size_t)64 * DIM, _d + 4096); \
} while (0)
#define STG_B(TT_, H_) do { \
    const unsigned short* _s = bgp + (size_t)(H_) * 128 * DIM + (TT_) * 64; \
    unsigned short* _d = &Bs[(TT_) & 1][H_][0] + (wave << 9); \
    glds16(_s, _d); glds16(_s + (size_t)64 * DIM, _d + 4096); \
} while (0)

#define MFMA_PH(IB, NQ) do { \
    __builtin_amdgcn_s_setprio(1); \
    _Pragma("unroll") \
    for (int ii = 0; ii < 4; ++ii) { \
        _Pragma("unroll") \
        for (int jj = 0; jj < 2; ++jj) { \
            floatx4 c_ = acc[(IB) + ii][(NQ) * 2 + jj]; \
            c_ = __builtin_amdgcn_mfma_f32_16x16x32_bf16( \
                __builtin_bit_cast(bf16x8, bv[NQ][jj][0]), \
                __builtin_bit_cast(bf16x8, av[ii][0]), c_, 0, 0, 0); \
            c_ = __builtin_amdgcn_mfma_f32_16x16x32_bf16( \
                __builtin_bit_cast(bf16x8, bv[NQ][jj][1]), \
                __builtin_bit_cast(bf16x8, av[ii][1]), c_, 0, 0, 0); \
            acc[(IB) + ii][(NQ) * 2 + jj] = c_; \
        } \
    } \
    __builtin_amdgcn_s_setprio(0); \
} while (0)

__global__ __launch_bounds__(512, 2) void k_gemm1(
    const unsigned short* __restrict__ zbf, const unsigned short* __restrict__ cbbf,
    const float* __restrict__ z2, const float* __restrict__ c2,
    const int* __restrict__ lengths, const int* __restrict__ stride_p,
    float* __restrict__ Sg, unsigned short* __restrict__ Eg) {
    // LDS: [dbuf][half(128rows)][128*64 bf16] for A and B = 128 KiB total
    __shared__ alignas(16) unsigned short As[2][2][8192];
    __shared__ alignas(16) unsigned short Bs[2][2][8192];
    __shared__ float z2s[256], c2s[256];
    __shared__ unsigned char vldp[256];
    __shared__ int s_any;

    int tid = threadIdx.x;
    // XCD-aware bijective swizzle (NWG2 % 8 == 0)
    int wg = blockIdx.x;
    int swz = (wg & 7) * (NWG2 / 8) + (wg >> 3);
    int bx = swz & (NTX2 - 1);
    int by = swz >> 4;
    int r0 = by * 256, c0 = bx * 256;

    if (tid == 0) s_any = 0;
    __syncthreads();
    if (tid < 256) {
        int n = r0 + tid;
        int valid = 0;
        if (n < NROWS) {
            int b = n / TT, t_ = n - b * TT;
            int nv = lengths[b] / stride_p[0];
            if (nv > TT) nv = TT;
            valid = (t_ < nv);
        }
        if (valid) atomicOr(&s_any, 1);
        vldp[tid] = (unsigned char)valid;
        z2s[tid] = z2[r0 + tid];
        c2s[tid] = c2[c0 + tid];
    }
    __syncthreads();
    if (!s_any) return;   // fully-masked row tile: contributes nothing

    int wave = tid >> 6, lane = tid & 63;
    int l15 = lane & 15, l4 = lane >> 4;
    int wr2 = wave >> 2;          // 0..1 -> M strip (interleaved, stride 32)
    int wc4 = wave & 3;           // 0..3 -> N strip (interleaved, stride 64)

    // staging lane geometry (8 rows per wave-load, source pre-swizzled)
    int srow8 = lane >> 3;
    int sg = (lane & 7) ^ srow8;
    const unsigned short* agp = zbf + (size_t)(r0 + wave * 8 + srow8) * DIM + sg * 8;
    const unsigned short* bgp = cbbf + (size_t)(c0 + wave * 8 + srow8) * DIM + sg * 8;

    // ds_read lane geometry
    unsigned AsB = (unsigned)(size_t)&As[0][0][0];
    unsigned BsB = (unsigned)(size_t)&Bs[0][0][0];
    unsigned rowA = (unsigned)((wr2 * 16 + l15) * 128);
    unsigned rowB = (unsigned)((wc4 * 16 + l15) * 128);
    unsigned p0 = (unsigned)(((l4) ^ (l15 & 7)) * 16);
    unsigned p1 = (unsigned)(((4 + l4) ^ (l15 & 7)) * 16);

    floatx4 acc[8][4];
    const floatx4 zacc = {0.f, 0.f, 0.f, 0.f};
#pragma unroll
    for (int i = 0; i < 8; ++i)
#pragma unroll
        for (int j = 0; j < 4; ++j) acc[i][j] = zacc;

    // prologue: stage t0{A0,B0,B1,A1}, t1{A0,B0}; allow newest 4 halves in flight
    STG_A(0, 0); STG_B(0, 0); STG_B(0, 1); STG_A(0, 1); STG_A(1, 0); STG_B(1, 0);
    asm volatile("s_waitcnt vmcnt(8)" ::: "memory");
    asm volatile("s_barrier" ::: "memory");

#pragma unroll
    for (int t = 0; t < KTILES; ++t) {
        unsigned dbase = (unsigned)((t & 1) * 32768);
        unsigned aAh0 = AsB + dbase + rowA;
        unsigned aAh1 = aAh0 + 16384u;
        unsigned aBh0 = BsB + dbase + rowB;
        unsigned aBh1 = aBh0 + 16384u;
        ushortx8 av[4][2];        // A fragments of current half (reused 2 phases)
        ushortx8 bv[2][2][2];     // B fragments of whole K-tile [nq][jj][ks]

        // ---- phase q0: read A-half0 + B-half0; stage B(t+1,h1)
        {
            unsigned a0 = aAh0 + p0, a1 = aAh0 + p1;
            DSR(av[0][0], a0); DSR(av[1][0], a0 + 4096u);
            DSR(av[2][0], a0 + 8192u); DSR(av[3][0], a0 + 12288u);
            DSR(av[0][1], a1); DSR(av[1][1], a1 + 4096u);
            DSR(av[2][1], a1 + 8192u); DSR(av[3][1], a1 + 12288u);
            unsigned b0 = aBh0 + p0, b1 = aBh0 + p1;
            DSR(bv[0][0][0], b0); DSR(bv[0][1][0], b0 + 8192u);
            DSR(bv[0][0][1], b1); DSR(bv[0][1][1], b1 + 8192u);
        }
        if (t + 1 < KTILES) STG_B(t + 1, 1);
        PIPE_SYNC();
        MFMA_PH(0, 0);
        PIPE_POST();

        // ---- phase q1: read B-half1; stage A(t+1,h1)
        {
            unsigned b0 = aBh1 + p0, b1 = aBh1 + p1;
            DSR(bv[1][0][0], b0); DSR(bv[1][1][0], b0 + 8192u);
            DSR(bv[1][0][1], b1); DSR(bv[1][1][1], b1 + 8192u);
        }
        if (t + 1 < KTILES) STG_A(t + 1, 1);
        PIPE_SYNC();
        MFMA_PH(0, 1);
        PIPE_POST();

        // ---- phase q2: read A-half1; stage A(t+2,h0)
        {
            unsigned a0 = aAh1 + p0, a1 = aAh1 + p1;
            DSR(av[0][0], a0); DSR(av[1][0], a0 + 4096u);
            DSR(av[2][0], a0 + 8192u); DSR(av[3][0], a0 + 12288u);
            DSR(av[0][1], a1); DSR(av[1][1], a1 + 4096u);
            DSR(av[2][1], a1 + 8192u); DSR(av[3][1], a1 + 12288u);
        }
        if (t + 2 < KTILES) STG_A(t + 2, 0);
        PIPE_SYNC();
        MFMA_PH(4, 0);
        PIPE_POST();

        // ---- phase q3: no reads; stage B(t+2,h0)
        if (t + 2 < KTILES) STG_B(t + 2, 0);
        PIPE_SYNC();
        MFMA_PH(4, 1);
        PIPE_POST();
    }

    // epilogue: e = exp(SHIFT - sqrt(z2+c2-2*dot)); S += row-sum; E[n][k] packed 8B
    // swapped-MFMA C/D layout: k = c0 + j*64 + wc4*16 + l4*4 + reg,
    //                          n = r0 + i*32 + wr2*16 + l15
    float c2r[4][4];
#pragma unroll
    for (int j = 0; j < 4; ++j)
#pragma unroll
        for (int r = 0; r < 4; ++r)
            c2r[j][r] = c2s[j * 64 + wc4 * 16 + l4 * 4 + r];

#pragma unroll
    for (int i = 0; i < 8; ++i) {
        int rl = i * 32 + wr2 * 16 + l15;
        bool rv = vldp[rl] != 0;
        float z2v = z2s[rl];
        float s = 0.f;
        unsigned short* Ep = Eg + (size_t)(r0 + rl) * NCODES + c0 + wc4 * 16 + l4 * 4;
#pragma unroll
        for (int j = 0; j < 4; ++j) {
            float e[4];
#pragma unroll
            for (int r = 0; r < 4; ++r) {
                float d2 = z2v + c2r[j][r] - 2.0f * acc[i][j][r];
                float d = sqrtf(fmaxf(d2, 1e-12f));
                e[r] = __expf(SHIFTC - d);
                s += e[r];
            }
            if (rv) {
                unsigned h0 = __builtin_bit_cast(unsigned short, __float2bfloat16(e[0]));
                unsigned h1 = __builtin_bit_cast(unsigned short, __float2bfloat16(e[1]));
                unsigned h2 = __builtin_bit_cast(unsigned short, __float2bfloat16(e[2]));
                unsigned h3 = __builtin_bit_cast(unsigned short, __float2bfloat16(e[3]));
                uint2 o;
                o.x = h0 | (h1 << 16);
                o.y = h2 | (h3 << 16);
                *(uint2*)(Ep + (size_t)j * 64) = o;
            }
        }
        s += __shfl_xor(s, 16); s += __shfl_xor(s, 32);
        if (l4 == 0 && rv) atomicAdd(&Sg[r0 + rl], s);
    }
}

// ---------------- pass 2: memory-bound scan  cdp[slice][k] += E[n][k]/S[n] ------
__global__ __launch_bounds__(256) void k_scan(
    const unsigned short* __restrict__ Eg, const float* __restrict__ Sg,
    const int* __restrict__ lengths, const int* __restrict__ stride_p,
    float* __restrict__ cdp) {
    __shared__ float rs[32];
    __shared__ int s_any;
    int tid = threadIdx.x;
    int r0 = blockIdx.y * 32;
    if (tid == 0) s_any = 0;
    __syncthreads();
    if (tid < 32) {
        int n = r0 + tid;
        int valid = 0;
        if (n < NROWS) {
            int b = n / TT, t = n - b * TT;
            int nv = lengths[b] / stride_p[0];
            if (nv > TT) nv = TT;
            valid = (t < nv);
        }
        if (valid) atomicOr(&s_any, 1);
        rs[tid] = valid ? 1.0f / Sg[n] : 0.0f;
    }
    __syncthreads();
    if (!s_any) return;

    int col0 = blockIdx.x * 2048 + tid * 8;
    float acc[8] = {0.f, 0.f, 0.f, 0.f, 0.f, 0.f, 0.f, 0.f};
    for (int nn = 0; nn < 32; ++nn) {
        float rn = rs[nn];
        if (rn == 0.f) continue;        // wave-uniform: prefix-mask rows skip
        uint4 v = *(const uint4*)(Eg + (size_t)(r0 + nn) * NCODES + col0);
        unsigned int u[4] = {v.x, v.y, v.z, v.w};
#pragma unroll
        for (int q = 0; q < 4; ++q) {
            acc[2 * q]     += rn * __builtin_bit_cast(float, u[q] << 16);
            acc[2 * q + 1] += rn * __builtin_bit_cast(float, u[q] & 0xffff0000u);
        }
    }
    float* outp = cdp + (size_t)(blockIdx.y & (NSLICE - 1)) * NCODES;
#pragma unroll
    for (int t = 0; t < 8; ++t) atomicAdd(&outp[col0 + t], acc[t]);
}

// ---------------- fallback (small ws): two-pass GEMM (writes cdp slice 0) -------
template <int PASS>
__global__ __launch_bounds__(256, 2) void k_gemm(
    const unsigned short* __restrict__ zbf, const unsigned short* __restrict__ cbbf,
    const float* __restrict__ z2, const float* __restrict__ c2,
    const int* __restrict__ lengths, const int* __restrict__ stride_p,
    float* __restrict__ Sg, float* __restrict__ cd) {
    __shared__ unsigned short Asf[128 * 64];
    __shared__ unsigned short Bsf[128 * 64];
    __shared__ float z2s[128], c2s[128], rs[128];
    __shared__ int s_any;
    int tid = threadIdx.x;
    int r0 = blockIdx.y * 128, c0 = blockIdx.x * 128;
    if (tid == 0) s_any = 0;
    __syncthreads();
    if (tid < 128) {
        int n = r0 + tid;
        int valid = 0;
        if (n < NROWS) {
            int b = n / TT, t = n - b * TT;
            int stride = stride_p[0];
            int nv = lengths[b] / stride;
            if (nv > TT) nv = TT;
            valid = (t < nv);
        }
        if (valid) atomicOr(&s_any, 1);
        z2s[tid] = z2[r0 + tid];
        c2s[tid] = c2[c0 + tid];
        if (PASS == 2) rs[tid] = valid ? (1.0f / Sg[r0 + tid]) : 0.0f;
    }
    __syncthreads();
    if (!s_any) return;

    int wave = tid >> 6, lane = tid & 63;
    int l15 = lane & 15, l4 = lane >> 4;
    int wr = (wave >> 1) * 64, wc = (wave & 1) * 64;
    int srow = lane >> 3;
    int scg = (lane & 7) ^ srow;
    const unsigned short* ag = zbf + (size_t)(r0 + wave * 32 + srow) * DIM + scg * 8;
    const unsigned short* bg = cbbf + (size_t)(c0 + wave * 32 + srow) * DIM + scg * 8;
    unsigned short* al = Asf + (wave * 32) * 64;
    unsigned short* bl = Bsf + (wave * 32) * 64;

    floatx4 acc[4][4];
    const floatx4 zero = {0.f, 0.f, 0.f, 0.f};
#pragma unroll
    for (int i = 0; i < 4; ++i)
#pragma unroll
        for (int j = 0; j < 4; ++j) acc[i][j] = zero;
    int sw = l15 & 7;
    for (int kc = 0; kc < 8; ++kc) {
#pragma unroll
        for (int q = 0; q < 4; ++q) {
            glds16(ag + (size_t)q * 8 * DIM + kc * 64, al + q * 8 * 64);
            glds16(bg + (size_t)q * 8 * DIM + kc * 64, bl + q * 8 * 64);
        }
        __syncthreads();
#pragma unroll
        for (int ks = 0; ks < 64; ks += 32) {
            int g = (ks >> 3) + l4;
            int pcg = g ^ sw;
            bf16x8 av[4], bvv[4];
#pragma unroll
            for (int i = 0; i < 4; ++i)
                av[i] = __builtin_bit_cast(bf16x8, *(const ushortx8*)&Asf[(wr + 16 * i + l15) * 64 + pcg * 8]);
#pragma unroll
            for (int j = 0; j < 4; ++j)
                bvv[j] = __builtin_bit_cast(bf16x8, *(const ushortx8*)&Bsf[(wc + 16 * j + l15) * 64 + pcg * 8]);
#pragma unroll
            for (int i = 0; i < 4; ++i)
#pragma unroll
                for (int j = 0; j < 4; ++j)
                    acc[i][j] = __builtin_amdgcn_mfma_f32_16x16x32_bf16(av[i], bvv[j], acc[i][j], 0, 0, 0);
        }
        __syncthreads();
    }
    if (PASS == 1) {
#pragma unroll
        for (int i = 0; i < 4; ++i) {
#pragma unroll
            for (int r = 0; r < 4; ++r) {
                int rl = wr + 16 * i + 4 * l4 + r;
                float z2v = z2s[rl];
                float s = 0.f;
#pragma unroll
                for (int j = 0; j < 4; ++j) {
                    int cl = wc + 16 * j + l15;
                    float d2 = z2v + c2s[cl] - 2.0f * acc[i][j][r];
                    float d = sqrtf(fmaxf(d2, 1e-12f));
                    s += __expf(SHIFTC - d);
                }
                s += __shfl_xor(s, 1); s += __shfl_xor(s, 2);
                s += __shfl_xor(s, 4); s += __shfl_xor(s, 8);
                if (l15 == 0) atomicAdd(&Sg[r0 + rl], s);
            }
        }
    } else {
#pragma unroll
        for (int j = 0; j < 4; ++j) {
            int cl = wc + 16 * j + l15;
            float c2v = c2s[cl];
            float cs = 0.f;
#pragma unroll
            for (int i = 0; i < 4; ++i) {
#pragma unroll
                for (int r = 0; r < 4; ++r) {
                    int rl = wr + 16 * i + 4 * l4 + r;
                    float d2 = z2s[rl] + c2v - 2.0f * acc[i][j][r];
                    float d = sqrtf(fmaxf(d2, 1e-12f));
                    cs += __expf(SHIFTC - d) * rs[rl];
                }
            }
            cs += __shfl_xor(cs, 16); cs += __shfl_xor(cs, 32);
            if (l4 == 0) atomicAdd(&cd[c0 + cl], cs);
        }
    }
}

// ---------------- finalize: reduce slices, normalize, entropy (1024 thr) --------
__global__ __launch_bounds__(1024) void k_final(const float* __restrict__ cdp,
                                                float* __restrict__ out) {
    __shared__ float red[16];
    __shared__ float tot_s;
    int tid = threadIdx.x, lane = tid & 63, wave = tid >> 6;
    float vloc[4];
    float t = 0.f;
#pragma unroll
    for (int q = 0; q < 4; ++q) {
        int i = tid + q * 1024;
        float v = 0.f;
#pragma unroll
        for (int s = 0; s < NSLICE; ++s) v += cdp[(size_t)s * NCODES + i];
        vloc[q] = v;
        t += v;
    }
#pragma unroll
    for (int off = 32; off >= 1; off >>= 1) t += __shfl_down(t, off);
    if (lane == 0) red[wave] = t;
    __syncthreads();
    if (tid == 0) {
        float tt = 0.f;
#pragma unroll
        for (int w = 0; w < 16; ++w) tt += red[w];
        tot_s = tt;
    }
    __syncthreads();
    float inv = 1.0f / (tot_s + 1e-8f);
    float e = 0.f;
#pragma unroll
    for (int q = 0; q < 4; ++q) {
        float p = vloc[q] * inv;
        e += p * __logf(p + 1e-8f);
    }
#pragma unroll
    for (int off = 32; off >= 1; off >>= 1) e += __shfl_down(e, off);
    if (lane == 0) red[wave] = e;
    __syncthreads();
    if (tid == 0) {
        float ee = 0.f;
#pragma unroll
        for (int w = 0; w < 16; ++w) ee += red[w];
        out[0] = 1.0f - (-ee) / __logf((float)NCODES);
    }
}

// ---------------- launcher ----------------
extern "C" void kernel_launch(void* const* d_in, const int* in_sizes, int n_in,
                              void* d_out, int out_size, void* d_ws, size_t ws_size,
                              hipStream_t stream) {
    const float* sf = (const float*)d_in[0];
    const float* cb = (const float*)d_in[1];
    const int* lengths = (const int*)d_in[2];
    const int* stride_p = (const int*)d_in[3];

    float* wsf = (float*)d_ws;
    float* Sg = wsf;                                     // NROWS_PAD
    float* cdp = Sg + NROWS_PAD;                         // NSLICE*NCODES
    const size_t OFF_Z2 = NZERO;
    const size_t OFF_C2 = OFF_Z2 + NROWS_PAD;
    const size_t OFF_ZB = (OFF_C2 + NCODES + 3) & ~(size_t)3;  // 16B-align bf16 region
    float* z2 = wsf + OFF_Z2;
    float* c2 = wsf + OFF_C2;
    unsigned short* zbf = (unsigned short*)(wsf + OFF_ZB);     // NROWS_PAD*DIM bf16
    unsigned short* cbbf = zbf + (size_t)NROWS_PAD * DIM;      // NCODES*DIM bf16
    unsigned short* Eg = cbbf + (size_t)NCODES * DIM;          // NROWS_PAD*NCODES bf16

    size_t need = OFF_ZB * 4
                + ((size_t)NROWS_PAD * DIM + (size_t)NCODES * DIM
                 + (size_t)NROWS_PAD * NCODES) * 2;

    k_prep<<<dim3(TBLKS + CBLKS), 256, 0, stream>>>(sf, cb, zbf, cbbf, z2, c2, Sg);
    if (ws_size >= need) {
        k_gemm1<<<dim3(NWG2), 512, 0, stream>>>(
            zbf, cbbf, z2, c2, lengths, stride_p, Sg, Eg);
        k_scan<<<dim3(2, NROWS_PAD / 32), 256, 0, stream>>>(
            Eg, Sg, lengths, stride_p, cdp);
    } else {
        k_gemm<1><<<dim3(NBLKX, ROW_TILES), 256, 0, stream>>>(zbf, cbbf, z2, c2, lengths, stride_p, Sg, cdp);
        k_gemm<2><<<dim3(NBLKX, ROW_TILES), 256, 0, stream>>>(zbf, cbbf, z2, c2, lengths, stride_p, Sg, cdp);
    }
    k_final<<<1, 1024, 0, stream>>>(cdp, (float*)d_out);
}

// Round 2
// 256.548 us; speedup vs baseline: 1.2281x; 1.2281x over previous
//
#include <hip/hip_runtime.h>
#include <hip/hip_bf16.h>

// ---------------- problem constants (fixed by setup_inputs) ----------------
#define NUM_B   16
#define DIM     512
#define TT      1500
#define NROWS   (NUM_B * TT)              // 24000
#define NCODES  4096
#define ROW_TILES ((NROWS + 127) / 128)   // 188 (fallback path)
#define NROWS_PAD (ROW_TILES * 128)       // 24064
#define NSLICE  8                         // partial cd slices (atomic decontention)
#define SHIFTC  30.0f                     // exp shift: exp(SHIFT-d), cancels in softmax
#define NBLKX   (NCODES / 128)            // 32 col tiles (fallback path)
#define TBLKS   (NUM_B * 47)              // 752 transpose blocks (47 t-tiles of 32)
#define CBLKS   (NCODES / 4)              // 1024 cb blocks
#define NZERO   (NROWS_PAD + NSLICE * NCODES)   // Sg + cdp

// 256x256 8-phase gemm1 geometry
#define NTY2 (NROWS_PAD / 256)            // 94
#define NTX2 (NCODES / 256)               // 16
#define NWG2 (NTY2 * NTX2)                // 1504
#define KTILES (DIM / 64)                 // 8

typedef __bf16 bf16x8 __attribute__((ext_vector_type(8)));
typedef float  floatx4 __attribute__((ext_vector_type(4)));
typedef unsigned short ushortx8 __attribute__((ext_vector_type(8)));

// async global->LDS, 16B per lane; dest = wave-uniform base + lane*16
__device__ __forceinline__ void glds16(const void* g, void* l) {
    __builtin_amdgcn_global_load_lds(
        (__attribute__((address_space(1))) void*)(void*)g,
        (__attribute__((address_space(3))) void*)l, 16, 0, 0);
}

// ---------------- prep: transpose + z2 (register-accum) + cb + ws zeroing -------
__global__ __launch_bounds__(256) void k_prep(
    const float* __restrict__ sf, const float* __restrict__ cb,
    unsigned short* __restrict__ zbf, unsigned short* __restrict__ cbbf,
    float* __restrict__ z2, float* __restrict__ c2, float* __restrict__ zero0) {
    int id = blockIdx.x, tid = threadIdx.x;
    if (id < TBLKS) {
        __shared__ float tile[32][257];
        int b = id / 47, t0 = (id % 47) * 32;
        int tl = tid & 31, dg = tid >> 5;       // phase 1: t lane, d group (8x32)
        int tr = tid >> 3, dgr = tid & 7;       // phase 2: 8 lanes per t-row
        int tg = t0 + tr;
        float ssq = 0.f;
        unsigned short* dst = zbf + (size_t)(b * TT + tg) * DIM;
#pragma unroll
        for (int half = 0; half < 2; ++half) {
            int dbase = half * 256;
            if (half) __syncthreads();          // drain phase-2 reads of prev half
            int t = t0 + tl;
            if (t < TT) {
                const float* src = sf + (size_t)(b * DIM + dbase + dg * 32) * TT + t;
#pragma unroll
                for (int k = 0; k < 32; ++k)
                    tile[tl][dg * 32 + k] = src[(size_t)k * TT];
            }
            __syncthreads();
            if (tg < TT) {
#pragma unroll
                for (int seg = 0; seg < 4; ++seg) {
                    int d0 = seg * 64 + dgr * 8;
                    unsigned int h[8];
#pragma unroll
                    for (int i2 = 0; i2 < 8; ++i2) {
                        __hip_bfloat16 hb = __float2bfloat16(tile[tr][d0 + i2]);
                        h[i2] = __builtin_bit_cast(unsigned short, hb);
                        float vb = __bfloat162float(hb);
                        ssq += vb * vb;
                    }
                    uint4 o;
                    o.x = h[0] | (h[1] << 16); o.y = h[2] | (h[3] << 16);
                    o.z = h[4] | (h[5] << 16); o.w = h[6] | (h[7] << 16);
                    *(uint4*)(dst + dbase + d0) = o;
                }
            }
        }
        // reduce over the 8 lanes sharing tr (lane bits 0..2)
        ssq += __shfl_xor(ssq, 1); ssq += __shfl_xor(ssq, 2); ssq += __shfl_xor(ssq, 4);
        if (dgr == 0 && tg < TT) z2[b * TT + tg] = ssq;
    } else {
        int ci = id - TBLKS;
        int gid = ci * 256 + tid;
        if (gid < NZERO) zero0[gid] = 0.f;
        int k = ci * 4 + (tid >> 6);
        int lane = tid & 63;
        const float4* src = (const float4*)(cb + (size_t)k * DIM + lane * 8);
        float4 a = src[0], b2 = src[1];
        float vals[8] = {a.x, a.y, a.z, a.w, b2.x, b2.y, b2.z, b2.w};
        float s = 0.f;
        unsigned int h[8];
#pragma unroll
        for (int i = 0; i < 8; ++i) {
            __hip_bfloat16 hb = __float2bfloat16(vals[i]);
            h[i] = __builtin_bit_cast(unsigned short, hb);
            float vb = __bfloat162float(hb);
            s += vb * vb;
        }
        uint4 o;
        o.x = h[0] | (h[1] << 16); o.y = h[2] | (h[3] << 16);
        o.z = h[4] | (h[5] << 16); o.w = h[6] | (h[7] << 16);
        *(uint4*)(cbbf + (size_t)k * DIM + lane * 8) = o;
#pragma unroll
        for (int off = 32; off >= 1; off >>= 1) s += __shfl_down(s, off);
        if (lane == 0) c2[k] = s;
    }
}

// ---------------- pass 1: 256x256 4-phase/K-tile GEMM + exp epilogue ------------
// 8 waves (2M x 4N), BK=64, double-buffered LDS. Counted vmcnt(4) ONCE per K-tile
// (T4), one barrier per phase, read-side XOR swizzle (T2), setprio (T5).
// Stage rotation: q0:A(t+1,h1) q1:B(t+1,h1) q2:A(t+2,h0) q3:B(t+2,h0).
// vmcnt math: at q3's wait, <=6 stages (12 loads) outstanding; tile t+1 needs the
// oldest 4 stages done -> allow newest 2 stages = vmcnt(4). Overflow stages
// (t+1/t+2 >= KTILES) are issued unconditionally into dead LDS regions to keep
// the outstanding count uniform (targets verified dead vs all remaining reads).

#define DSR(dst, addr) asm volatile("ds_read_b128 %0, %1" : "=v"(dst) : "v"(addr))
#define BARR() asm volatile("s_barrier" ::: "memory")
#define WAIT_LGKM() do { \
    asm volatile("s_waitcnt lgkmcnt(0)" ::: "memory"); \
    __builtin_amdgcn_sched_barrier(0); \
} while (0)
#define VMC4() asm volatile("s_waitcnt vmcnt(4)" ::: "memory")

#define STG_A(TT_, H_) do { \
    const unsigned short* _s = agp + (size_t)(H_) * 128 * DIM + (TT_) * 64; \
    unsigned short* _d = &As[(TT_) & 1][H_][0] + (wave << 9); \
    glds16(_s, _d); glds16(_s + (size_t)64 * DIM, _d + 4096); \
} while (0)
#define STG_B(TT_, H_) do { \
    const unsigned short* _s = bgp + (size_t)(H_) * 128 * DIM + (TT_) * 64; \
    unsigned short* _d = &Bs[(TT_) & 1][H_][0] + (wave << 9); \
    glds16(_s, _d); glds16(_s + (size_t)64 * DIM, _d + 4096); \
} while (0)

// 16 MFMA: rows IB..IB+3 x cols JB..JB+1 over K=64 (2 k-slices)
#define MFMA16(IB, BV, JB) do { \
    __builtin_amdgcn_s_setprio(1); \
    _Pragma("unroll") \
    for (int ii = 0; ii < 4; ++ii) { \
        _Pragma("unroll") \
        for (int jj = 0; jj < 2; ++jj) { \
            floatx4 c_ = acc[(IB) + ii][(JB) + jj]; \
            c_ = __builtin_amdgcn_mfma_f32_16x16x32_bf16( \
                __builtin_bit_cast(bf16x8, BV[jj][0]), \
                __builtin_bit_cast(bf16x8, av[ii][0]), c_, 0, 0, 0); \
            c_ = __builtin_amdgcn_mfma_f32_16x16x32_bf16( \
                __builtin_bit_cast(bf16x8, BV[jj][1]), \
                __builtin_bit_cast(bf16x8, av[ii][1]), c_, 0, 0, 0); \
            acc[(IB) + ii][(JB) + jj] = c_; \
        } \
    } \
    __builtin_amdgcn_s_setprio(0); \
} while (0)

__global__ __launch_bounds__(512, 2) void k_gemm1(
    const unsigned short* __restrict__ zbf, const unsigned short* __restrict__ cbbf,
    const float* __restrict__ z2, const float* __restrict__ c2,
    const int* __restrict__ lengths, const int* __restrict__ stride_p,
    float* __restrict__ Sg, unsigned short* __restrict__ Eg) {
    // LDS: [dbuf][half(128rows)][128x64 bf16] for A and B = 128 KiB total
    __shared__ alignas(16) unsigned short As[2][2][8192];
    __shared__ alignas(16) unsigned short Bs[2][2][8192];
    __shared__ float z2s[256], c2s[256];
    __shared__ unsigned char vldp[256];
    __shared__ int s_any;

    int tid = threadIdx.x;
    // XCD mapping: xcd owns 2 bx columns, walks by with bx-pair inner.
    // B-panels (512 KB/XCD) stay L2-resident; A-panel's 2nd visit is an L2 hit.
    int wg = blockIdx.x;
    int xcd = wg & 7;
    int idx = wg >> 3;                 // 0..187
    int by = idx >> 1;                 // 0..93
    int bx = xcd * 2 + (idx & 1);      // 0..15
    int r0 = by * 256, c0 = bx * 256;

    if (tid == 0) s_any = 0;
    __syncthreads();
    if (tid < 256) {
        int n = r0 + tid;
        int valid = 0;
        if (n < NROWS) {
            int b = n / TT, t_ = n - b * TT;
            int nv = lengths[b] / stride_p[0];
            if (nv > TT) nv = TT;
            valid = (t_ < nv);
        }
        if (valid) atomicOr(&s_any, 1);
        vldp[tid] = (unsigned char)valid;
        z2s[tid] = z2[r0 + tid];
        c2s[tid] = c2[c0 + tid];
    }
    __syncthreads();
    if (!s_any) return;   // fully-masked row tile: contributes nothing

    int wave = tid >> 6, lane = tid & 63;
    int l15 = lane & 15, l4 = lane >> 4;
    int wr2 = wave >> 2;          // 0..1 -> M strip (interleaved, stride 32)
    int wc4 = wave & 3;           // 0..3 -> N strip (interleaved, stride 64)

    // staging lane geometry (8 rows per wave-load, source pre-swizzled)
    int srow8 = lane >> 3;
    int sg = (lane & 7) ^ srow8;
    const unsigned short* agp = zbf + (size_t)(r0 + wave * 8 + srow8) * DIM + sg * 8;
    const unsigned short* bgp = cbbf + (size_t)(c0 + wave * 8 + srow8) * DIM + sg * 8;

    // ds_read lane geometry
    unsigned AsB = (unsigned)(size_t)&As[0][0][0];
    unsigned BsB = (unsigned)(size_t)&Bs[0][0][0];
    unsigned rowA = (unsigned)((wr2 * 16 + l15) * 128);
    unsigned rowB = (unsigned)((wc4 * 16 + l15) * 128);
    unsigned p0 = (unsigned)(((l4) ^ (l15 & 7)) * 16);
    unsigned p1 = (unsigned)(((4 + l4) ^ (l15 & 7)) * 16);

    floatx4 acc[8][4];
    const floatx4 zacc = {0.f, 0.f, 0.f, 0.f};
#pragma unroll
    for (int i = 0; i < 8; ++i)
#pragma unroll
        for (int j = 0; j < 4; ++j) acc[i][j] = zacc;

    // prologue: tile0 fully + tile1 h0s; allow newest 2 stages (4 loads) in flight
    STG_A(0, 0); STG_B(0, 0); STG_A(0, 1); STG_B(0, 1); STG_A(1, 0); STG_B(1, 0);
    VMC4();
    BARR();

    ushortx8 av[4][2];        // A fragments of current half [rowtile][ks]
    ushortx8 bv0[2][2];       // B cols 0..1 fragments [jj][ks] (live q0->q2)
    ushortx8 bv1[2][2];       // B cols 2..3 fragments [jj][ks] (live q1->q3)

#pragma unroll
    for (int t = 0; t < KTILES; ++t) {
        unsigned dbase = (unsigned)((t & 1) * 32768);
        unsigned aA = AsB + dbase + rowA;
        unsigned aB = BsB + dbase + rowB;

        // ---- q0: read A-h0 (8) + B-h0 (4); stage A(t+1,h1)
        DSR(av[0][0], aA + p0); DSR(av[1][0], aA + 4096u + p0);
        DSR(av[2][0], aA + 8192u + p0); DSR(av[3][0], aA + 12288u + p0);
        DSR(av[0][1], aA + p1); DSR(av[1][1], aA + 4096u + p1);
        DSR(av[2][1], aA + 8192u + p1); DSR(av[3][1], aA + 12288u + p1);
        DSR(bv0[0][0], aB + p0); DSR(bv0[1][0], aB + 8192u + p0);
        DSR(bv0[0][1], aB + p1); DSR(bv0[1][1], aB + 8192u + p1);
        STG_A(t + 1, 1);
        BARR(); WAIT_LGKM();
        MFMA16(0, bv0, 0);

        // ---- q1: read B-h1 (4); stage B(t+1,h1)
        DSR(bv1[0][0], aB + 16384u + p0); DSR(bv1[1][0], aB + 24576u + p0);
        DSR(bv1[0][1], aB + 16384u + p1); DSR(bv1[1][1], aB + 24576u + p1);
        STG_B(t + 1, 1);
        BARR(); WAIT_LGKM();
        MFMA16(0, bv1, 2);

        // ---- q2: read A-h1 (8, overwrite av); stage A(t+2,h0)
        DSR(av[0][0], aA + 16384u + p0); DSR(av[1][0], aA + 20480u + p0);
        DSR(av[2][0], aA + 24576u + p0); DSR(av[3][0], aA + 28672u + p0);
        DSR(av[0][1], aA + 16384u + p1); DSR(av[1][1], aA + 20480u + p1);
        DSR(av[2][1], aA + 24576u + p1); DSR(av[3][1], aA + 28672u + p1);
        STG_A(t + 2, 0);
        BARR(); WAIT_LGKM();
        MFMA16(4, bv0, 0);

        // ---- q3: stage B(t+2,h0); counted vmcnt for tile t+1; barrier
        STG_B(t + 2, 0);
        VMC4();
        BARR();
        MFMA16(4, bv1, 2);
    }

    // epilogue: e = exp(SHIFT - sqrt(z2+c2-2*dot)); S += row-sum; E[n][k] packed 8B
    // swapped-MFMA C/D layout: k = c0 + j*64 + wc4*16 + l4*4 + reg,
    //                          n = r0 + i*32 + wr2*16 + l15
    float c2r[4][4];
#pragma unroll
    for (int j = 0; j < 4; ++j)
#pragma unroll
        for (int r = 0; r < 4; ++r)
            c2r[j][r] = c2s[j * 64 + wc4 * 16 + l4 * 4 + r];

#pragma unroll
    for (int i = 0; i < 8; ++i) {
        int rl = i * 32 + wr2 * 16 + l15;
        bool rv = vldp[rl] != 0;
        float z2v = z2s[rl];
        float s = 0.f;
        unsigned short* Ep = Eg + (size_t)(r0 + rl) * NCODES + c0 + wc4 * 16 + l4 * 4;
#pragma unroll
        for (int j = 0; j < 4; ++j) {
            float e[4];
#pragma unroll
            for (int r = 0; r < 4; ++r) {
                float d2 = z2v + c2r[j][r] - 2.0f * acc[i][j][r];
                float d = sqrtf(fmaxf(d2, 1e-12f));
                e[r] = __expf(SHIFTC - d);
                s += e[r];
            }
            if (rv) {
                unsigned h0 = __builtin_bit_cast(unsigned short, __float2bfloat16(e[0]));
                unsigned h1 = __builtin_bit_cast(unsigned short, __float2bfloat16(e[1]));
                unsigned h2 = __builtin_bit_cast(unsigned short, __float2bfloat16(e[2]));
                unsigned h3 = __builtin_bit_cast(unsigned short, __float2bfloat16(e[3]));
                uint2 o;
                o.x = h0 | (h1 << 16);
                o.y = h2 | (h3 << 16);
                *(uint2*)(Ep + (size_t)j * 64) = o;
            }
        }
        s += __shfl_xor(s, 16); s += __shfl_xor(s, 32);
        if (l4 == 0 && rv) atomicAdd(&Sg[r0 + rl], s);
    }
}

// ---------------- pass 2: memory-bound scan  cdp[slice][k] += E[n][k]/S[n] ------
__global__ __launch_bounds__(256) void k_scan(
    const unsigned short* __restrict__ Eg, const float* __restrict__ Sg,
    const int* __restrict__ lengths, const int* __restrict__ stride_p,
    float* __restrict__ cdp) {
    __shared__ float rs[32];
    __shared__ int s_any;
    int tid = threadIdx.x;
    int r0 = blockIdx.y * 32;
    if (tid == 0) s_any = 0;
    __syncthreads();
    if (tid < 32) {
        int n = r0 + tid;
        int valid = 0;
        if (n < NROWS) {
            int b = n / TT, t = n - b * TT;
            int nv = lengths[b] / stride_p[0];
            if (nv > TT) nv = TT;
            valid = (t < nv);
        }
        if (valid) atomicOr(&s_any, 1);
        rs[tid] = valid ? 1.0f / Sg[n] : 0.0f;
    }
    __syncthreads();
    if (!s_any) return;

    int col0 = blockIdx.x * 2048 + tid * 8;
    float acc[8] = {0.f, 0.f, 0.f, 0.f, 0.f, 0.f, 0.f, 0.f};
    for (int nn = 0; nn < 32; ++nn) {
        float rn = rs[nn];
        if (rn == 0.f) continue;        // wave-uniform: prefix-mask rows skip
        uint4 v = *(const uint4*)(Eg + (size_t)(r0 + nn) * NCODES + col0);
        unsigned int u[4] = {v.x, v.y, v.z, v.w};
#pragma unroll
        for (int q = 0; q < 4; ++q) {
            acc[2 * q]     += rn * __builtin_bit_cast(float, u[q] << 16);
            acc[2 * q + 1] += rn * __builtin_bit_cast(float, u[q] & 0xffff0000u);
        }
    }
    float* outp = cdp + (size_t)(blockIdx.y & (NSLICE - 1)) * NCODES;
#pragma unroll
    for (int t = 0; t < 8; ++t) atomicAdd(&outp[col0 + t], acc[t]);
}

// ---------------- fallback (small ws): two-pass GEMM (writes cdp slice 0) -------
template <int PASS>
__global__ __launch_bounds__(256, 2) void k_gemm(
    const unsigned short* __restrict__ zbf, const unsigned short* __restrict__ cbbf,
    const float* __restrict__ z2, const float* __restrict__ c2,
    const int* __restrict__ lengths, const int* __restrict__ stride_p,
    float* __restrict__ Sg, float* __restrict__ cd) {
    __shared__ unsigned short Asf[128 * 64];
    __shared__ unsigned short Bsf[128 * 64];
    __shared__ float z2s[128], c2s[128], rs[128];
    __shared__ int s_any;
    int tid = threadIdx.x;
    int r0 = blockIdx.y * 128, c0 = blockIdx.x * 128;
    if (tid == 0) s_any = 0;
    __syncthreads();
    if (tid < 128) {
        int n = r0 + tid;
        int valid = 0;
        if (n < NROWS) {
            int b = n / TT, t = n - b * TT;
            int stride = stride_p[0];
            int nv = lengths[b] / stride;
            if (nv > TT) nv = TT;
            valid = (t < nv);
        }
        if (valid) atomicOr(&s_any, 1);
        z2s[tid] = z2[r0 + tid];
        c2s[tid] = c2[c0 + tid];
        if (PASS == 2) rs[tid] = valid ? (1.0f / Sg[r0 + tid]) : 0.0f;
    }
    __syncthreads();
    if (!s_any) return;

    int wave = tid >> 6, lane = tid & 63;
    int l15 = lane & 15, l4 = lane >> 4;
    int wr = (wave >> 1) * 64, wc = (wave & 1) * 64;
    int srow = lane >> 3;
    int scg = (lane & 7) ^ srow;
    const unsigned short* ag = zbf + (size_t)(r0 + wave * 32 + srow) * DIM + scg * 8;
    const unsigned short* bg = cbbf + (size_t)(c0 + wave * 32 + srow) * DIM + scg * 8;
    unsigned short* al = Asf + (wave * 32) * 64;
    unsigned short* bl = Bsf + (wave * 32) * 64;

    floatx4 acc[4][4];
    const floatx4 zero = {0.f, 0.f, 0.f, 0.f};
#pragma unroll
    for (int i = 0; i < 4; ++i)
#pragma unroll
        for (int j = 0; j < 4; ++j) acc[i][j] = zero;
    int sw = l15 & 7;
    for (int kc = 0; kc < 8; ++kc) {
#pragma unroll
        for (int q = 0; q < 4; ++q) {
            glds16(ag + (size_t)q * 8 * DIM + kc * 64, al + q * 8 * 64);
            glds16(bg + (size_t)q * 8 * DIM + kc * 64, bl + q * 8 * 64);
        }
        __syncthreads();
#pragma unroll
        for (int ks = 0; ks < 64; ks += 32) {
            int g = (ks >> 3) + l4;
            int pcg = g ^ sw;
            bf16x8 av[4], bvv[4];
#pragma unroll
            for (int i = 0; i < 4; ++i)
                av[i] = __builtin_bit_cast(bf16x8, *(const ushortx8*)&Asf[(wr + 16 * i + l15) * 64 + pcg * 8]);
#pragma unroll
            for (int j = 0; j < 4; ++j)
                bvv[j] = __builtin_bit_cast(bf16x8, *(const ushortx8*)&Bsf[(wc + 16 * j + l15) * 64 + pcg * 8]);
#pragma unroll
            for (int i = 0; i < 4; ++i)
#pragma unroll
                for (int j = 0; j < 4; ++j)
                    acc[i][j] = __builtin_amdgcn_mfma_f32_16x16x32_bf16(av[i], bvv[j], acc[i][j], 0, 0, 0);
        }
        __syncthreads();
    }
    if (PASS == 1) {
#pragma unroll
        for (int i = 0; i < 4; ++i) {
#pragma unroll
            for (int r = 0; r < 4; ++r) {
                int rl = wr + 16 * i + 4 * l4 + r;
                float z2v = z2s[rl];
                float s = 0.f;
#pragma unroll
                for (int j = 0; j < 4; ++j) {
                    int cl = wc + 16 * j + l15;
                    float d2 = z2v + c2s[cl] - 2.0f * acc[i][j][r];
                    float d = sqrtf(fmaxf(d2, 1e-12f));
                    s += __expf(SHIFTC - d);
                }
                s += __shfl_xor(s, 1); s += __shfl_xor(s, 2);
                s += __shfl_xor(s, 4); s += __shfl_xor(s, 8);
                if (l15 == 0) atomicAdd(&Sg[r0 + rl], s);
            }
        }
    } else {
#pragma unroll
        for (int j = 0; j < 4; ++j) {
            int cl = wc + 16 * j + l15;
            float c2v = c2s[cl];
            float cs = 0.f;
#pragma unroll
            for (int i = 0; i < 4; ++i) {
#pragma unroll
                for (int r = 0; r < 4; ++r) {
                    int rl = wr + 16 * i + 4 * l4 + r;
                    float d2 = z2s[rl] + c2v - 2.0f * acc[i][j][r];
                    float d = sqrtf(fmaxf(d2, 1e-12f));
                    cs += __expf(SHIFTC - d) * rs[rl];
                }
            }
            cs += __shfl_xor(cs, 16); cs += __shfl_xor(cs, 32);
            if (l4 == 0) atomicAdd(&cd[c0 + cl], cs);
        }
    }
}

// ---------------- finalize: reduce slices, normalize, entropy (1024 thr) --------
__global__ __launch_bounds__(1024) void k_final(const float* __restrict__ cdp,
                                                float* __restrict__ out) {
    __shared__ float red[16];
    __shared__ float tot_s;
    int tid = threadIdx.x, lane = tid & 63, wave = tid >> 6;
    float vloc[4];
    float t = 0.f;
#pragma unroll
    for (int q = 0; q < 4; ++q) {
        int i = tid + q * 1024;
        float v = 0.f;
#pragma unroll
        for (int s = 0; s < NSLICE; ++s) v += cdp[(size_t)s * NCODES + i];
        vloc[q] = v;
        t += v;
    }
#pragma unroll
    for (int off = 32; off >= 1; off >>= 1) t += __shfl_down(t, off);
    if (lane == 0) red[wave] = t;
    __syncthreads();
    if (tid == 0) {
        float tt = 0.f;
#pragma unroll
        for (int w = 0; w < 16; ++w) tt += red[w];
        tot_s = tt;
    }
    __syncthreads();
    float inv = 1.0f / (tot_s + 1e-8f);
    float e = 0.f;
#pragma unroll
    for (int q = 0; q < 4; ++q) {
        float p = vloc[q] * inv;
        e += p * __logf(p + 1e-8f);
    }
#pragma unroll
    for (int off = 32; off >= 1; off >>= 1) e += __shfl_down(e, off);
    if (lane == 0) red[wave] = e;
    __syncthreads();
    if (tid == 0) {
        float ee = 0.f;
#pragma unroll
        for (int w = 0; w < 16; ++w) ee += red[w];
        out[0] = 1.0f - (-ee) / __logf((float)NCODES);
    }
}

// ---------------- launcher ----------------
extern "C" void kernel_launch(void* const* d_in, const int* in_sizes, int n_in,
                              void* d_out, int out_size, void* d_ws, size_t ws_size,
                              hipStream_t stream) {
    const float* sf = (const float*)d_in[0];
    const float* cb = (const float*)d_in[1];
    const int* lengths = (const int*)d_in[2];
    const int* stride_p = (const int*)d_in[3];

    float* wsf = (float*)d_ws;
    float* Sg = wsf;                                     // NROWS_PAD
    float* cdp = Sg + NROWS_PAD;                         // NSLICE*NCODES
    const size_t OFF_Z2 = NZERO;
    const size_t OFF_C2 = OFF_Z2 + NROWS_PAD;
    const size_t OFF_ZB = (OFF_C2 + NCODES + 3) & ~(size_t)3;  // 16B-align bf16 region
    float* z2 = wsf + OFF_Z2;
    float* c2 = wsf + OFF_C2;
    unsigned short* zbf = (unsigned short*)(wsf + OFF_ZB);     // NROWS_PAD*DIM bf16
    unsigned short* cbbf = zbf + (size_t)NROWS_PAD * DIM;      // NCODES*DIM bf16
    unsigned short* Eg = cbbf + (size_t)NCODES * DIM;          // NROWS_PAD*NCODES bf16

    size_t need = OFF_ZB * 4
                + ((size_t)NROWS_PAD * DIM + (size_t)NCODES * DIM
                 + (size_t)NROWS_PAD * NCODES) * 2;

    k_prep<<<dim3(TBLKS + CBLKS), 256, 0, stream>>>(sf, cb, zbf, cbbf, z2, c2, Sg);
    if (ws_size >= need) {
        k_gemm1<<<dim3(NWG2), 512, 0, stream>>>(
            zbf, cbbf, z2, c2, lengths, stride_p, Sg, Eg);
        k_scan<<<dim3(2, NROWS_PAD / 32), 256, 0, stream>>>(
            Eg, Sg, lengths, stride_p, cdp);
    } else {
        k_gemm<1><<<dim3(NBLKX, ROW_TILES), 256, 0, stream>>>(zbf, cbbf, z2, c2, lengths, stride_p, Sg, cdp);
        k_gemm<2><<<dim3(NBLKX, ROW_TILES), 256, 0, stream>>>(zbf, cbbf, z2, c2, lengths, stride_p, Sg, cdp);
    }
    k_final<<<1, 1024, 0, stream>>>(cdp, (float*)d_out);
}

// Round 3
// 232.838 us; speedup vs baseline: 1.3531x; 1.1018x over previous
//
#include <hip/hip_runtime.h>
#include <hip/hip_bf16.h>

// ---------------- problem constants (fixed by setup_inputs) ----------------
#define NUM_B   16
#define DIM     512
#define TT      1500
#define NROWS   (NUM_B * TT)              // 24000
#define NCODES  4096
#define ROW_TILES ((NROWS + 127) / 128)   // 188
#define NROWS_PAD (ROW_TILES * 128)       // 24064
#define NSLICE  8                         // partial cd slices (atomic decontention)
#define SHIFTC  30.0f                     // exp shift: exp(SHIFT-d), cancels in softmax
#define NBLKX   (NCODES / 128)            // 32 col tiles
#define TBLKS   (NUM_B * 47)              // 752 transpose blocks (47 t-tiles of 32)
#define CBLKS   (NCODES / 4)              // 1024 cb blocks
#define NZERO   (NROWS_PAD + NSLICE * NCODES)   // Sg + cdp

typedef __bf16 bf16x8 __attribute__((ext_vector_type(8)));
typedef float  floatx4 __attribute__((ext_vector_type(4)));
typedef unsigned short ushortx8 __attribute__((ext_vector_type(8)));

// async global->LDS, 16B per lane; dest = wave-uniform base + lane*16
__device__ __forceinline__ void glds16(const void* g, void* l) {
    __builtin_amdgcn_global_load_lds(
        (__attribute__((address_space(1))) void*)(void*)g,
        (__attribute__((address_space(3))) void*)l, 16, 0, 0);
}

// ---------------- prep: transpose + z2 (register-accum) + cb + ws zeroing -------
// id < TBLKS: transpose block (b, t0): 2 phases of 32t x 256d, LDS stride 257
//   (257%32==1 -> phase-1 writes and phase-2 reads both <=2-way = free).
//   z2 accumulated in registers across phases -> no atomics, no pre-zero.
// id >= TBLKS: cb conversion block + zero Sg/cdp.
__global__ __launch_bounds__(256) void k_prep(
    const float* __restrict__ sf, const float* __restrict__ cb,
    unsigned short* __restrict__ zbf, unsigned short* __restrict__ cbbf,
    float* __restrict__ z2, float* __restrict__ c2, float* __restrict__ zero0) {
    int id = blockIdx.x, tid = threadIdx.x;
    if (id < TBLKS) {
        __shared__ float tile[32][257];
        int b = id / 47, t0 = (id % 47) * 32;
        int tl = tid & 31, dg = tid >> 5;       // phase 1: t lane, d group (8x32)
        int tr = tid >> 3, dgr = tid & 7;       // phase 2: 8 lanes per t-row
        int tg = t0 + tr;
        float ssq = 0.f;
        unsigned short* dst = zbf + (size_t)(b * TT + tg) * DIM;
#pragma unroll
        for (int half = 0; half < 2; ++half) {
            int dbase = half * 256;
            if (half) __syncthreads();          // drain phase-2 reads of prev half
            int t = t0 + tl;
            if (t < TT) {
                const float* src = sf + (size_t)(b * DIM + dbase + dg * 32) * TT + t;
#pragma unroll
                for (int k = 0; k < 32; ++k)
                    tile[tl][dg * 32 + k] = src[(size_t)k * TT];
            }
            __syncthreads();
            if (tg < TT) {
#pragma unroll
                for (int seg = 0; seg < 4; ++seg) {
                    int d0 = seg * 64 + dgr * 8;
                    unsigned int h[8];
#pragma unroll
                    for (int i2 = 0; i2 < 8; ++i2) {
                        __hip_bfloat16 hb = __float2bfloat16(tile[tr][d0 + i2]);
                        h[i2] = __builtin_bit_cast(unsigned short, hb);
                        float vb = __bfloat162float(hb);
                        ssq += vb * vb;
                    }
                    uint4 o;
                    o.x = h[0] | (h[1] << 16); o.y = h[2] | (h[3] << 16);
                    o.z = h[4] | (h[5] << 16); o.w = h[6] | (h[7] << 16);
                    *(uint4*)(dst + dbase + d0) = o;
                }
            }
        }
        // reduce over the 8 lanes sharing tr (lane bits 0..2)
        ssq += __shfl_xor(ssq, 1); ssq += __shfl_xor(ssq, 2); ssq += __shfl_xor(ssq, 4);
        if (dgr == 0 && tg < TT) z2[b * TT + tg] = ssq;
    } else {
        int ci = id - TBLKS;
        int gid = ci * 256 + tid;
        if (gid < NZERO) zero0[gid] = 0.f;
        int k = ci * 4 + (tid >> 6);
        int lane = tid & 63;
        const float4* src = (const float4*)(cb + (size_t)k * DIM + lane * 8);
        float4 a = src[0], b2 = src[1];
        float vals[8] = {a.x, a.y, a.z, a.w, b2.x, b2.y, b2.z, b2.w};
        float s = 0.f;
        unsigned int h[8];
#pragma unroll
        for (int i = 0; i < 8; ++i) {
            __hip_bfloat16 hb = __float2bfloat16(vals[i]);
            h[i] = __builtin_bit_cast(unsigned short, hb);
            float vb = __bfloat162float(hb);
            s += vb * vb;
        }
        uint4 o;
        o.x = h[0] | (h[1] << 16); o.y = h[2] | (h[3] << 16);
        o.z = h[4] | (h[5] << 16); o.w = h[6] | (h[7] << 16);
        *(uint4*)(cbbf + (size_t)k * DIM + lane * 8) = o;
#pragma unroll
        for (int off = 32; off >= 1; off >>= 1) s += __shfl_down(s, off);
        if (lane == 0) c2[k] = s;
    }
}

// ---------------- pass 1: GEMM + exp; accumulate S, store E bf16 ----------------
// Round-0 proven 128x128 2-phase structure. Only change: MFMA operands swapped
// (mfma(bv, av, acc) -> acc's 4 regs = 4 CONSECUTIVE codebook cols), enabling
// packed 8B E-stores (64 scalar stores -> 16 uint2), hoisted per-row valid/z2,
// and a 2-shuffle S reduction.
// Swapped C/D layout: row (n)  = wr + 16*i + (lane&15)
//                     col (k)  = wc + 16*j + (lane>>4)*4 + reg
__global__ __launch_bounds__(256, 2) void k_gemm1(
    const unsigned short* __restrict__ zbf, const unsigned short* __restrict__ cbbf,
    const float* __restrict__ z2, const float* __restrict__ c2,
    const int* __restrict__ lengths, const int* __restrict__ stride_p,
    float* __restrict__ Sg, unsigned short* __restrict__ Eg) {
    __shared__ unsigned short As[128 * 64];
    __shared__ unsigned short Bs[128 * 64];
    __shared__ float z2s[128], c2s[128];
    __shared__ unsigned char vldp[128];
    __shared__ int s_any;
    int tid = threadIdx.x;
    int r0 = blockIdx.y * 128, c0 = blockIdx.x * 128;
    if (tid == 0) s_any = 0;
    __syncthreads();
    if (tid < 128) {
        int n = r0 + tid;
        int valid = 0;
        if (n < NROWS) {
            int b = n / TT, t = n - b * TT;
            int stride = stride_p[0];
            int nv = lengths[b] / stride;
            if (nv > TT) nv = TT;
            valid = (t < nv);
        }
        if (valid) atomicOr(&s_any, 1);
        vldp[tid] = (unsigned char)valid;
        z2s[tid] = z2[r0 + tid];
        c2s[tid] = c2[c0 + tid];
    }
    __syncthreads();
    if (!s_any) return;   // fully-masked row tile: contributes nothing

    int wave = tid >> 6, lane = tid & 63;
    int l15 = lane & 15, l4 = lane >> 4;
    int wr = (wave >> 1) * 64, wc = (wave & 1) * 64;

    int srow = lane >> 3;
    int scg = (lane & 7) ^ srow;
    const unsigned short* ag = zbf + (size_t)(r0 + wave * 32 + srow) * DIM + scg * 8;
    const unsigned short* bg = cbbf + (size_t)(c0 + wave * 32 + srow) * DIM + scg * 8;
    unsigned short* al = As + (wave * 32) * 64;
    unsigned short* bl = Bs + (wave * 32) * 64;

    floatx4 acc[4][4];
    const floatx4 zero = {0.f, 0.f, 0.f, 0.f};
#pragma unroll
    for (int i = 0; i < 4; ++i)
#pragma unroll
        for (int j = 0; j < 4; ++j) acc[i][j] = zero;

    int sw = l15 & 7;

    for (int kc = 0; kc < 8; ++kc) {
#pragma unroll
        for (int q = 0; q < 4; ++q) {
            glds16(ag + (size_t)q * 8 * DIM + kc * 64, al + q * 8 * 64);
            glds16(bg + (size_t)q * 8 * DIM + kc * 64, bl + q * 8 * 64);
        }
        __syncthreads();
#pragma unroll
        for (int ks = 0; ks < 64; ks += 32) {
            int g = (ks >> 3) + l4;
            int pcg = g ^ sw;
            bf16x8 av[4], bv[4];
#pragma unroll
            for (int i = 0; i < 4; ++i)
                av[i] = __builtin_bit_cast(bf16x8,
                    *(const ushortx8*)&As[(wr + 16 * i + l15) * 64 + pcg * 8]);
#pragma unroll
            for (int j = 0; j < 4; ++j)
                bv[j] = __builtin_bit_cast(bf16x8,
                    *(const ushortx8*)&Bs[(wc + 16 * j + l15) * 64 + pcg * 8]);
#pragma unroll
            for (int i = 0; i < 4; ++i)
#pragma unroll
                for (int j = 0; j < 4; ++j)
                    acc[i][j] = __builtin_amdgcn_mfma_f32_16x16x32_bf16(bv[j], av[i], acc[i][j], 0, 0, 0);
        }
        __syncthreads();
    }

    // epilogue: e = exp(SHIFT - sqrt(z2+c2-2*dot)); S += row-sum; E[n][k] packed 8B
    float c2r[4][4];
#pragma unroll
    for (int j = 0; j < 4; ++j)
#pragma unroll
        for (int r = 0; r < 4; ++r)
            c2r[j][r] = c2s[wc + 16 * j + 4 * l4 + r];

#pragma unroll
    for (int i = 0; i < 4; ++i) {
        int rl = wr + 16 * i + l15;
        bool rv = vldp[rl] != 0;
        float z2v = z2s[rl];
        float s = 0.f;
        unsigned short* Ep = Eg + (size_t)(r0 + rl) * NCODES + c0 + wc + l4 * 4;
#pragma unroll
        for (int j = 0; j < 4; ++j) {
            float e[4];
#pragma unroll
            for (int r = 0; r < 4; ++r) {
                float d2 = z2v + c2r[j][r] - 2.0f * acc[i][j][r];
                float d = sqrtf(fmaxf(d2, 1e-12f));
                e[r] = __expf(SHIFTC - d);
                s += e[r];
            }
            if (rv) {
                unsigned h0 = __builtin_bit_cast(unsigned short, __float2bfloat16(e[0]));
                unsigned h1 = __builtin_bit_cast(unsigned short, __float2bfloat16(e[1]));
                unsigned h2 = __builtin_bit_cast(unsigned short, __float2bfloat16(e[2]));
                unsigned h3 = __builtin_bit_cast(unsigned short, __float2bfloat16(e[3]));
                uint2 o;
                o.x = h0 | (h1 << 16);
                o.y = h2 | (h3 << 16);
                *(uint2*)(Ep + 16 * j) = o;
            }
        }
        s += __shfl_xor(s, 16); s += __shfl_xor(s, 32);
        if (l4 == 0 && rv) atomicAdd(&Sg[r0 + rl], s);
    }
}

// ---------------- pass 2: memory-bound scan  cdp[slice][k] += E[n][k]/S[n] ------
// Grid (2, 752): 32 rows x 2048 cols per block, 8 cols/thread. Valid rows are
// ballot-compacted into LDS, then processed 4-at-a-time with 4 independent
// uint4 loads in flight (4x MLP; the old loop was 1-deep load->fma->load).
__global__ __launch_bounds__(256) void k_scan(
    const unsigned short* __restrict__ Eg, const float* __restrict__ Sg,
    const int* __restrict__ lengths, const int* __restrict__ stride_p,
    float* __restrict__ cdp) {
    __shared__ float rs2[32];
    __shared__ unsigned char vrows[32];
    __shared__ int s_cnt;
    int tid = threadIdx.x;
    int r0 = blockIdx.y * 32;
    if (tid < 64) {                         // one wave: validity + compaction
        int valid = 0;
        float inv = 0.f;
        if (tid < 32) {
            int n = r0 + tid;
            if (n < NROWS) {
                int b = n / TT, t = n - b * TT;
                int nv = lengths[b] / stride_p[0];
                if (nv > TT) nv = TT;
                valid = (t < nv);
                if (valid) inv = 1.0f / Sg[n];
            }
        }
        unsigned long long mask = __ballot(valid);
        if (tid == 0) s_cnt = __popcll(mask);
        if (valid) {
            int pos = __popcll(mask & ((1ull << tid) - 1ull));
            vrows[pos] = (unsigned char)tid;
            rs2[pos] = inv;
        }
    }
    __syncthreads();
    int m = s_cnt;
    if (m == 0) return;

    int col0 = blockIdx.x * 2048 + tid * 8;
    const unsigned short* base = Eg + (size_t)r0 * NCODES + col0;
    float acc[8] = {0.f, 0.f, 0.f, 0.f, 0.f, 0.f, 0.f, 0.f};

#define ACC8(V, RN) do { \
    unsigned int _u[4] = {(V).x, (V).y, (V).z, (V).w}; \
    _Pragma("unroll") \
    for (int q = 0; q < 4; ++q) { \
        acc[2 * q]     += (RN) * __builtin_bit_cast(float, _u[q] << 16); \
        acc[2 * q + 1] += (RN) * __builtin_bit_cast(float, _u[q] & 0xffff0000u); \
    } \
} while (0)

    int i = 0;
    for (; i + 4 <= m; i += 4) {
        uint4 v0 = *(const uint4*)(base + (size_t)vrows[i]     * NCODES);
        uint4 v1 = *(const uint4*)(base + (size_t)vrows[i + 1] * NCODES);
        uint4 v2 = *(const uint4*)(base + (size_t)vrows[i + 2] * NCODES);
        uint4 v3 = *(const uint4*)(base + (size_t)vrows[i + 3] * NCODES);
        float a0 = rs2[i], a1 = rs2[i + 1], a2 = rs2[i + 2], a3 = rs2[i + 3];
        ACC8(v0, a0); ACC8(v1, a1); ACC8(v2, a2); ACC8(v3, a3);
    }
    for (; i < m; ++i) {
        uint4 v = *(const uint4*)(base + (size_t)vrows[i] * NCODES);
        ACC8(v, rs2[i]);
    }
#undef ACC8

    float* outp = cdp + (size_t)(blockIdx.y & (NSLICE - 1)) * NCODES;
#pragma unroll
    for (int t = 0; t < 8; ++t) atomicAdd(&outp[col0 + t], acc[t]);
}

// ---------------- fallback (small ws): two-pass GEMM (writes cdp slice 0) -------
template <int PASS>
__global__ __launch_bounds__(256, 2) void k_gemm(
    const unsigned short* __restrict__ zbf, const unsigned short* __restrict__ cbbf,
    const float* __restrict__ z2, const float* __restrict__ c2,
    const int* __restrict__ lengths, const int* __restrict__ stride_p,
    float* __restrict__ Sg, float* __restrict__ cd) {
    __shared__ unsigned short Asf[128 * 64];
    __shared__ unsigned short Bsf[128 * 64];
    __shared__ float z2s[128], c2s[128], rs[128];
    __shared__ int s_any;
    int tid = threadIdx.x;
    int r0 = blockIdx.y * 128, c0 = blockIdx.x * 128;
    if (tid == 0) s_any = 0;
    __syncthreads();
    if (tid < 128) {
        int n = r0 + tid;
        int valid = 0;
        if (n < NROWS) {
            int b = n / TT, t = n - b * TT;
            int stride = stride_p[0];
            int nv = lengths[b] / stride;
            if (nv > TT) nv = TT;
            valid = (t < nv);
        }
        if (valid) atomicOr(&s_any, 1);
        z2s[tid] = z2[r0 + tid];
        c2s[tid] = c2[c0 + tid];
        if (PASS == 2) rs[tid] = valid ? (1.0f / Sg[r0 + tid]) : 0.0f;
    }
    __syncthreads();
    if (!s_any) return;

    int wave = tid >> 6, lane = tid & 63;
    int l15 = lane & 15, l4 = lane >> 4;
    int wr = (wave >> 1) * 64, wc = (wave & 1) * 64;
    int srow = lane >> 3;
    int scg = (lane & 7) ^ srow;
    const unsigned short* ag = zbf + (size_t)(r0 + wave * 32 + srow) * DIM + scg * 8;
    const unsigned short* bg = cbbf + (size_t)(c0 + wave * 32 + srow) * DIM + scg * 8;
    unsigned short* al = Asf + (wave * 32) * 64;
    unsigned short* bl = Bsf + (wave * 32) * 64;

    floatx4 acc[4][4];
    const floatx4 zero = {0.f, 0.f, 0.f, 0.f};
#pragma unroll
    for (int i = 0; i < 4; ++i)
#pragma unroll
        for (int j = 0; j < 4; ++j) acc[i][j] = zero;
    int sw = l15 & 7;
    for (int kc = 0; kc < 8; ++kc) {
#pragma unroll
        for (int q = 0; q < 4; ++q) {
            glds16(ag + (size_t)q * 8 * DIM + kc * 64, al + q * 8 * 64);
            glds16(bg + (size_t)q * 8 * DIM + kc * 64, bl + q * 8 * 64);
        }
        __syncthreads();
#pragma unroll
        for (int ks = 0; ks < 64; ks += 32) {
            int g = (ks >> 3) + l4;
            int pcg = g ^ sw;
            bf16x8 av[4], bvv[4];
#pragma unroll
            for (int i = 0; i < 4; ++i)
                av[i] = __builtin_bit_cast(bf16x8, *(const ushortx8*)&Asf[(wr + 16 * i + l15) * 64 + pcg * 8]);
#pragma unroll
            for (int j = 0; j < 4; ++j)
                bvv[j] = __builtin_bit_cast(bf16x8, *(const ushortx8*)&Bsf[(wc + 16 * j + l15) * 64 + pcg * 8]);
#pragma unroll
            for (int i = 0; i < 4; ++i)
#pragma unroll
                for (int j = 0; j < 4; ++j)
                    acc[i][j] = __builtin_amdgcn_mfma_f32_16x16x32_bf16(av[i], bvv[j], acc[i][j], 0, 0, 0);
        }
        __syncthreads();
    }
    if (PASS == 1) {
#pragma unroll
        for (int i = 0; i < 4; ++i) {
#pragma unroll
            for (int r = 0; r < 4; ++r) {
                int rl = wr + 16 * i + 4 * l4 + r;
                float z2v = z2s[rl];
                float s = 0.f;
#pragma unroll
                for (int j = 0; j < 4; ++j) {
                    int cl = wc + 16 * j + l15;
                    float d2 = z2v + c2s[cl] - 2.0f * acc[i][j][r];
                    float d = sqrtf(fmaxf(d2, 1e-12f));
                    s += __expf(SHIFTC - d);
                }
                s += __shfl_xor(s, 1); s += __shfl_xor(s, 2);
                s += __shfl_xor(s, 4); s += __shfl_xor(s, 8);
                if (l15 == 0) atomicAdd(&Sg[r0 + rl], s);
            }
        }
    } else {
#pragma unroll
        for (int j = 0; j < 4; ++j) {
            int cl = wc + 16 * j + l15;
            float c2v = c2s[cl];
            float cs = 0.f;
#pragma unroll
            for (int i = 0; i < 4; ++i) {
#pragma unroll
                for (int r = 0; r < 4; ++r) {
                    int rl = wr + 16 * i + 4 * l4 + r;
                    float d2 = z2s[rl] + c2v - 2.0f * acc[i][j][r];
                    float d = sqrtf(fmaxf(d2, 1e-12f));
                    cs += __expf(SHIFTC - d) * rs[rl];
                }
            }
            cs += __shfl_xor(cs, 16); cs += __shfl_xor(cs, 32);
            if (l4 == 0) atomicAdd(&cd[c0 + cl], cs);
        }
    }
}

// ---------------- finalize: reduce slices, normalize, entropy (1024 thr) --------
__global__ __launch_bounds__(1024) void k_final(const float* __restrict__ cdp,
                                                float* __restrict__ out) {
    __shared__ float red[16];
    __shared__ float tot_s;
    int tid = threadIdx.x, lane = tid & 63, wave = tid >> 6;
    float vloc[4];
    float t = 0.f;
#pragma unroll
    for (int q = 0; q < 4; ++q) {
        int i = tid + q * 1024;
        float v = 0.f;
#pragma unroll
        for (int s = 0; s < NSLICE; ++s) v += cdp[(size_t)s * NCODES + i];
        vloc[q] = v;
        t += v;
    }
#pragma unroll
    for (int off = 32; off >= 1; off >>= 1) t += __shfl_down(t, off);
    if (lane == 0) red[wave] = t;
    __syncthreads();
    if (tid == 0) {
        float tt = 0.f;
#pragma unroll
        for (int w = 0; w < 16; ++w) tt += red[w];
        tot_s = tt;
    }
    __syncthreads();
    float inv = 1.0f / (tot_s + 1e-8f);
    float e = 0.f;
#pragma unroll
    for (int q = 0; q < 4; ++q) {
        float p = vloc[q] * inv;
        e += p * __logf(p + 1e-8f);
    }
#pragma unroll
    for (int off = 32; off >= 1; off >>= 1) e += __shfl_down(e, off);
    if (lane == 0) red[wave] = e;
    __syncthreads();
    if (tid == 0) {
        float ee = 0.f;
#pragma unroll
        for (int w = 0; w < 16; ++w) ee += red[w];
        out[0] = 1.0f - (-ee) / __logf((float)NCODES);
    }
}

// ---------------- launcher ----------------
extern "C" void kernel_launch(void* const* d_in, const int* in_sizes, int n_in,
                              void* d_out, int out_size, void* d_ws, size_t ws_size,
                              hipStream_t stream) {
    const float* sf = (const float*)d_in[0];
    const float* cb = (const float*)d_in[1];
    const int* lengths = (const int*)d_in[2];
    const int* stride_p = (const int*)d_in[3];

    float* wsf = (float*)d_ws;
    float* Sg = wsf;                                     // NROWS_PAD
    float* cdp = Sg + NROWS_PAD;                         // NSLICE*NCODES
    const size_t OFF_Z2 = NZERO;
    const size_t OFF_C2 = OFF_Z2 + NROWS_PAD;
    const size_t OFF_ZB = (OFF_C2 + NCODES + 3) & ~(size_t)3;  // 16B-align bf16 region
    float* z2 = wsf + OFF_Z2;
    float* c2 = wsf + OFF_C2;
    unsigned short* zbf = (unsigned short*)(wsf + OFF_ZB);     // NROWS_PAD*DIM bf16
    unsigned short* cbbf = zbf + (size_t)NROWS_PAD * DIM;      // NCODES*DIM bf16
    unsigned short* Eg = cbbf + (size_t)NCODES * DIM;          // NROWS_PAD*NCODES bf16

    size_t need = OFF_ZB * 4
                + ((size_t)NROWS_PAD * DIM + (size_t)NCODES * DIM
                 + (size_t)NROWS_PAD * NCODES) * 2;

    k_prep<<<dim3(TBLKS + CBLKS), 256, 0, stream>>>(sf, cb, zbf, cbbf, z2, c2, Sg);
    if (ws_size >= need) {
        k_gemm1<<<dim3(NBLKX, ROW_TILES), 256, 0, stream>>>(
            zbf, cbbf, z2, c2, lengths, stride_p, Sg, Eg);
        k_scan<<<dim3(2, NROWS_PAD / 32), 256, 0, stream>>>(
            Eg, Sg, lengths, stride_p, cdp);
    } else {
        k_gemm<1><<<dim3(NBLKX, ROW_TILES), 256, 0, stream>>>(zbf, cbbf, z2, c2, lengths, stride_p, Sg, cdp);
        k_gemm<2><<<dim3(NBLKX, ROW_TILES), 256, 0, stream>>>(zbf, cbbf, z2, c2, lengths, stride_p, Sg, cdp);
    }
    k_final<<<1, 1024, 0, stream>>>(cdp, (float*)d_out);
}

// Round 4
// 224.115 us; speedup vs baseline: 1.4058x; 1.0389x over previous
//
#include <hip/hip_runtime.h>
#include <hip/hip_bf16.h>

// ---------------- problem constants (fixed by setup_inputs) ----------------
#define NUM_B   16
#define DIM     512
#define TT      1500
#define NROWS   (NUM_B * TT)              // 24000
#define NCODES  4096
#define ROW_TILES ((NROWS + 127) / 128)   // 188
#define NROWS_PAD (ROW_TILES * 128)       // 24064
#define NSLICE  8                         // partial cd slices (atomic decontention)
#define SHIFTC  30.0f                     // exp shift: exp(SHIFT-d), cancels in softmax
#define NBLKX   (NCODES / 128)            // 32 col tiles
#define TBLKS   (NUM_B * 47)              // 752 transpose blocks (47 t-tiles of 32)
#define CBLKS   (NCODES / 4)              // 1024 cb blocks
#define NZERO   (NROWS_PAD + NSLICE * NCODES)   // Sg + cdp
#define NZERO2  (NZERO + 1)               // + tot scalar

typedef __bf16 bf16x8 __attribute__((ext_vector_type(8)));
typedef float  floatx4 __attribute__((ext_vector_type(4)));
typedef unsigned short ushortx8 __attribute__((ext_vector_type(8)));

// async global->LDS, 16B per lane; dest = wave-uniform base + lane*16
__device__ __forceinline__ void glds16(const void* g, void* l) {
    __builtin_amdgcn_global_load_lds(
        (__attribute__((address_space(1))) void*)(void*)g,
        (__attribute__((address_space(3))) void*)l, 16, 0, 0);
}

// ---------------- prep: transpose + z2 (register-accum) + cb + ws zeroing -------
// id < TBLKS: transpose block (b, t0): 2 phases of 32t x 256d, LDS stride 257
//   (257%32==1 -> phase-1 writes and phase-2 reads both <=2-way = free).
//   z2 accumulated in registers across phases -> no atomics, no pre-zero.
// id >= TBLKS: cb conversion block + zero Sg/cdp/tot; ci==0 inits out=1.0
//   (loss = 1 + sum p*log(p+eps)/logK accumulated by k_ent).
__global__ __launch_bounds__(256) void k_prep(
    const float* __restrict__ sf, const float* __restrict__ cb,
    unsigned short* __restrict__ zbf, unsigned short* __restrict__ cbbf,
    float* __restrict__ z2, float* __restrict__ c2, float* __restrict__ zero0,
    float* __restrict__ outp) {
    int id = blockIdx.x, tid = threadIdx.x;
    if (id < TBLKS) {
        __shared__ float tile[32][257];
        int b = id / 47, t0 = (id % 47) * 32;
        int tl = tid & 31, dg = tid >> 5;       // phase 1: t lane, d group (8x32)
        int tr = tid >> 3, dgr = tid & 7;       // phase 2: 8 lanes per t-row
        int tg = t0 + tr;
        float ssq = 0.f;
        unsigned short* dst = zbf + (size_t)(b * TT + tg) * DIM;
#pragma unroll
        for (int half = 0; half < 2; ++half) {
            int dbase = half * 256;
            if (half) __syncthreads();          // drain phase-2 reads of prev half
            int t = t0 + tl;
            if (t < TT) {
                const float* src = sf + (size_t)(b * DIM + dbase + dg * 32) * TT + t;
#pragma unroll
                for (int k = 0; k < 32; ++k)
                    tile[tl][dg * 32 + k] = src[(size_t)k * TT];
            }
            __syncthreads();
            if (tg < TT) {
#pragma unroll
                for (int seg = 0; seg < 4; ++seg) {
                    int d0 = seg * 64 + dgr * 8;
                    unsigned int h[8];
#pragma unroll
                    for (int i2 = 0; i2 < 8; ++i2) {
                        __hip_bfloat16 hb = __float2bfloat16(tile[tr][d0 + i2]);
                        h[i2] = __builtin_bit_cast(unsigned short, hb);
                        float vb = __bfloat162float(hb);
                        ssq += vb * vb;
                    }
                    uint4 o;
                    o.x = h[0] | (h[1] << 16); o.y = h[2] | (h[3] << 16);
                    o.z = h[4] | (h[5] << 16); o.w = h[6] | (h[7] << 16);
                    *(uint4*)(dst + dbase + d0) = o;
                }
            }
        }
        // reduce over the 8 lanes sharing tr (lane bits 0..2)
        ssq += __shfl_xor(ssq, 1); ssq += __shfl_xor(ssq, 2); ssq += __shfl_xor(ssq, 4);
        if (dgr == 0 && tg < TT) z2[b * TT + tg] = ssq;
    } else {
        int ci = id - TBLKS;
        int gid = ci * 256 + tid;
        if (gid < NZERO2) zero0[gid] = 0.f;
        if (ci == 0 && tid == 0) outp[0] = 1.0f;
        int k = ci * 4 + (tid >> 6);
        int lane = tid & 63;
        const float4* src = (const float4*)(cb + (size_t)k * DIM + lane * 8);
        float4 a = src[0], b2 = src[1];
        float vals[8] = {a.x, a.y, a.z, a.w, b2.x, b2.y, b2.z, b2.w};
        float s = 0.f;
        unsigned int h[8];
#pragma unroll
        for (int i = 0; i < 8; ++i) {
            __hip_bfloat16 hb = __float2bfloat16(vals[i]);
            h[i] = __builtin_bit_cast(unsigned short, hb);
            float vb = __bfloat162float(hb);
            s += vb * vb;
        }
        uint4 o;
        o.x = h[0] | (h[1] << 16); o.y = h[2] | (h[3] << 16);
        o.z = h[4] | (h[5] << 16); o.w = h[6] | (h[7] << 16);
        *(uint4*)(cbbf + (size_t)k * DIM + lane * 8) = o;
#pragma unroll
        for (int off = 32; off >= 1; off >>= 1) s += __shfl_down(s, off);
        if (lane == 0) c2[k] = s;
    }
}

// ---------------- pass 1: GEMM + exp; accumulate S, store E bf16 ----------------
// Proven 128x128 2-phase structure; MFMA operands swapped (mfma(bv, av, acc) ->
// acc's 4 regs = 4 CONSECUTIVE codebook cols), packed 8B E-stores.
// Swapped C/D layout: row (n)  = wr + 16*i + (lane&15)
//                     col (k)  = wc + 16*j + (lane>>4)*4 + reg
__global__ __launch_bounds__(256, 2) void k_gemm1(
    const unsigned short* __restrict__ zbf, const unsigned short* __restrict__ cbbf,
    const float* __restrict__ z2, const float* __restrict__ c2,
    const int* __restrict__ lengths, const int* __restrict__ stride_p,
    float* __restrict__ Sg, unsigned short* __restrict__ Eg) {
    __shared__ unsigned short As[128 * 64];
    __shared__ unsigned short Bs[128 * 64];
    __shared__ float z2s[128], c2s[128];
    __shared__ unsigned char vldp[128];
    __shared__ int s_any;
    int tid = threadIdx.x;
    int r0 = blockIdx.y * 128, c0 = blockIdx.x * 128;
    if (tid == 0) s_any = 0;
    __syncthreads();
    if (tid < 128) {
        int n = r0 + tid;
        int valid = 0;
        if (n < NROWS) {
            int b = n / TT, t = n - b * TT;
            int stride = stride_p[0];
            int nv = lengths[b] / stride;
            if (nv > TT) nv = TT;
            valid = (t < nv);
        }
        if (valid) atomicOr(&s_any, 1);
        vldp[tid] = (unsigned char)valid;
        z2s[tid] = z2[r0 + tid];
        c2s[tid] = c2[c0 + tid];
    }
    __syncthreads();
    if (!s_any) return;   // fully-masked row tile: contributes nothing

    int wave = tid >> 6, lane = tid & 63;
    int l15 = lane & 15, l4 = lane >> 4;
    int wr = (wave >> 1) * 64, wc = (wave & 1) * 64;

    int srow = lane >> 3;
    int scg = (lane & 7) ^ srow;
    const unsigned short* ag = zbf + (size_t)(r0 + wave * 32 + srow) * DIM + scg * 8;
    const unsigned short* bg = cbbf + (size_t)(c0 + wave * 32 + srow) * DIM + scg * 8;
    unsigned short* al = As + (wave * 32) * 64;
    unsigned short* bl = Bs + (wave * 32) * 64;

    floatx4 acc[4][4];
    const floatx4 zero = {0.f, 0.f, 0.f, 0.f};
#pragma unroll
    for (int i = 0; i < 4; ++i)
#pragma unroll
        for (int j = 0; j < 4; ++j) acc[i][j] = zero;

    int sw = l15 & 7;

    for (int kc = 0; kc < 8; ++kc) {
#pragma unroll
        for (int q = 0; q < 4; ++q) {
            glds16(ag + (size_t)q * 8 * DIM + kc * 64, al + q * 8 * 64);
            glds16(bg + (size_t)q * 8 * DIM + kc * 64, bl + q * 8 * 64);
        }
        __syncthreads();
#pragma unroll
        for (int ks = 0; ks < 64; ks += 32) {
            int g = (ks >> 3) + l4;
            int pcg = g ^ sw;
            bf16x8 av[4], bv[4];
#pragma unroll
            for (int i = 0; i < 4; ++i)
                av[i] = __builtin_bit_cast(bf16x8,
                    *(const ushortx8*)&As[(wr + 16 * i + l15) * 64 + pcg * 8]);
#pragma unroll
            for (int j = 0; j < 4; ++j)
                bv[j] = __builtin_bit_cast(bf16x8,
                    *(const ushortx8*)&Bs[(wc + 16 * j + l15) * 64 + pcg * 8]);
#pragma unroll
            for (int i = 0; i < 4; ++i)
#pragma unroll
                for (int j = 0; j < 4; ++j)
                    acc[i][j] = __builtin_amdgcn_mfma_f32_16x16x32_bf16(bv[j], av[i], acc[i][j], 0, 0, 0);
        }
        __syncthreads();
    }

    // epilogue: e = exp(SHIFT - sqrt(z2+c2-2*dot)); S += row-sum; E[n][k] packed 8B
    float c2r[4][4];
#pragma unroll
    for (int j = 0; j < 4; ++j)
#pragma unroll
        for (int r = 0; r < 4; ++r)
            c2r[j][r] = c2s[wc + 16 * j + 4 * l4 + r];

#pragma unroll
    for (int i = 0; i < 4; ++i) {
        int rl = wr + 16 * i + l15;
        bool rv = vldp[rl] != 0;
        float z2v = z2s[rl];
        float s = 0.f;
        unsigned short* Ep = Eg + (size_t)(r0 + rl) * NCODES + c0 + wc + l4 * 4;
#pragma unroll
        for (int j = 0; j < 4; ++j) {
            float e[4];
#pragma unroll
            for (int r = 0; r < 4; ++r) {
                float d2 = z2v + c2r[j][r] - 2.0f * acc[i][j][r];
                float d = sqrtf(fmaxf(d2, 1e-12f));
                e[r] = __expf(SHIFTC - d);
                s += e[r];
            }
            if (rv) {
                unsigned h0 = __builtin_bit_cast(unsigned short, __float2bfloat16(e[0]));
                unsigned h1 = __builtin_bit_cast(unsigned short, __float2bfloat16(e[1]));
                unsigned h2 = __builtin_bit_cast(unsigned short, __float2bfloat16(e[2]));
                unsigned h3 = __builtin_bit_cast(unsigned short, __float2bfloat16(e[3]));
                uint2 o;
                o.x = h0 | (h1 << 16);
                o.y = h2 | (h3 << 16);
                *(uint2*)(Ep + 16 * j) = o;
            }
        }
        s += __shfl_xor(s, 16); s += __shfl_xor(s, 32);
        if (l4 == 0 && rv) atomicAdd(&Sg[r0 + rl], s);
    }
}

// ---------------- pass 2: memory-bound scan  cdp[slice][k] += E[n][k]/S[n] ------
// Grid (2, 376): 64 rows x 2048 cols per block, 8 cols/thread. Valid rows
// ballot-compacted into LDS; processed 8-at-a-time (8 independent uint4 loads
// in flight). 64-row windows halve the endgame atomic count vs 32-row
// (1.54M vs 3.08M device atomicAdds) at unchanged read traffic.
__global__ __launch_bounds__(256) void k_scan(
    const unsigned short* __restrict__ Eg, const float* __restrict__ Sg,
    const int* __restrict__ lengths, const int* __restrict__ stride_p,
    float* __restrict__ cdp) {
    __shared__ float rs2[64];
    __shared__ unsigned char vrows[64];
    __shared__ int s_cnt;
    int tid = threadIdx.x;
    int r0 = blockIdx.y * 64;
    if (tid < 64) {                         // one wave: validity + compaction
        int valid = 0;
        float inv = 0.f;
        int n = r0 + tid;
        if (n < NROWS) {
            int b = n / TT, t = n - b * TT;
            int nv = lengths[b] / stride_p[0];
            if (nv > TT) nv = TT;
            valid = (t < nv);
            if (valid) inv = 1.0f / Sg[n];
        }
        unsigned long long mask = __ballot(valid);
        if (tid == 0) s_cnt = __popcll(mask);
        if (valid) {
            int pos = __popcll(mask & ((1ull << tid) - 1ull));
            vrows[pos] = (unsigned char)tid;
            rs2[pos] = inv;
        }
    }
    __syncthreads();
    int m = s_cnt;
    if (m == 0) return;

    int col0 = blockIdx.x * 2048 + tid * 8;
    const unsigned short* base = Eg + (size_t)r0 * NCODES + col0;
    float acc[8] = {0.f, 0.f, 0.f, 0.f, 0.f, 0.f, 0.f, 0.f};

#define ACC8(V, RN) do { \
    unsigned int _u[4] = {(V).x, (V).y, (V).z, (V).w}; \
    _Pragma("unroll") \
    for (int q = 0; q < 4; ++q) { \
        acc[2 * q]     += (RN) * __builtin_bit_cast(float, _u[q] << 16); \
        acc[2 * q + 1] += (RN) * __builtin_bit_cast(float, _u[q] & 0xffff0000u); \
    } \
} while (0)

    int i = 0;
    for (; i + 8 <= m; i += 8) {
        uint4 v0 = *(const uint4*)(base + (size_t)vrows[i]     * NCODES);
        uint4 v1 = *(const uint4*)(base + (size_t)vrows[i + 1] * NCODES);
        uint4 v2 = *(const uint4*)(base + (size_t)vrows[i + 2] * NCODES);
        uint4 v3 = *(const uint4*)(base + (size_t)vrows[i + 3] * NCODES);
        uint4 v4 = *(const uint4*)(base + (size_t)vrows[i + 4] * NCODES);
        uint4 v5 = *(const uint4*)(base + (size_t)vrows[i + 5] * NCODES);
        uint4 v6 = *(const uint4*)(base + (size_t)vrows[i + 6] * NCODES);
        uint4 v7 = *(const uint4*)(base + (size_t)vrows[i + 7] * NCODES);
        ACC8(v0, rs2[i]);     ACC8(v1, rs2[i + 1]);
        ACC8(v2, rs2[i + 2]); ACC8(v3, rs2[i + 3]);
        ACC8(v4, rs2[i + 4]); ACC8(v5, rs2[i + 5]);
        ACC8(v6, rs2[i + 6]); ACC8(v7, rs2[i + 7]);
    }
    for (; i < m; ++i) {
        uint4 v = *(const uint4*)(base + (size_t)vrows[i] * NCODES);
        ACC8(v, rs2[i]);
    }
#undef ACC8

    float* outp = cdp + (size_t)(blockIdx.y & (NSLICE - 1)) * NCODES;
#pragma unroll
    for (int t = 0; t < 8; ++t) atomicAdd(&outp[col0 + t], acc[t]);
}

// ---------------- fallback (small ws): two-pass GEMM (writes cdp slice 0) -------
template <int PASS>
__global__ __launch_bounds__(256, 2) void k_gemm(
    const unsigned short* __restrict__ zbf, const unsigned short* __restrict__ cbbf,
    const float* __restrict__ z2, const float* __restrict__ c2,
    const int* __restrict__ lengths, const int* __restrict__ stride_p,
    float* __restrict__ Sg, float* __restrict__ cd) {
    __shared__ unsigned short Asf[128 * 64];
    __shared__ unsigned short Bsf[128 * 64];
    __shared__ float z2s[128], c2s[128], rs[128];
    __shared__ int s_any;
    int tid = threadIdx.x;
    int r0 = blockIdx.y * 128, c0 = blockIdx.x * 128;
    if (tid == 0) s_any = 0;
    __syncthreads();
    if (tid < 128) {
        int n = r0 + tid;
        int valid = 0;
        if (n < NROWS) {
            int b = n / TT, t = n - b * TT;
            int stride = stride_p[0];
            int nv = lengths[b] / stride;
            if (nv > TT) nv = TT;
            valid = (t < nv);
        }
        if (valid) atomicOr(&s_any, 1);
        z2s[tid] = z2[r0 + tid];
        c2s[tid] = c2[c0 + tid];
        if (PASS == 2) rs[tid] = valid ? (1.0f / Sg[r0 + tid]) : 0.0f;
    }
    __syncthreads();
    if (!s_any) return;

    int wave = tid >> 6, lane = tid & 63;
    int l15 = lane & 15, l4 = lane >> 4;
    int wr = (wave >> 1) * 64, wc = (wave & 1) * 64;
    int srow = lane >> 3;
    int scg = (lane & 7) ^ srow;
    const unsigned short* ag = zbf + (size_t)(r0 + wave * 32 + srow) * DIM + scg * 8;
    const unsigned short* bg = cbbf + (size_t)(c0 + wave * 32 + srow) * DIM + scg * 8;
    unsigned short* al = Asf + (wave * 32) * 64;
    unsigned short* bl = Bsf + (wave * 32) * 64;

    floatx4 acc[4][4];
    const floatx4 zero = {0.f, 0.f, 0.f, 0.f};
#pragma unroll
    for (int i = 0; i < 4; ++i)
#pragma unroll
        for (int j = 0; j < 4; ++j) acc[i][j] = zero;
    int sw = l15 & 7;
    for (int kc = 0; kc < 8; ++kc) {
#pragma unroll
        for (int q = 0; q < 4; ++q) {
            glds16(ag + (size_t)q * 8 * DIM + kc * 64, al + q * 8 * 64);
            glds16(bg + (size_t)q * 8 * DIM + kc * 64, bl + q * 8 * 64);
        }
        __syncthreads();
#pragma unroll
        for (int ks = 0; ks < 64; ks += 32) {
            int g = (ks >> 3) + l4;
            int pcg = g ^ sw;
            bf16x8 av[4], bvv[4];
#pragma unroll
            for (int i = 0; i < 4; ++i)
                av[i] = __builtin_bit_cast(bf16x8, *(const ushortx8*)&Asf[(wr + 16 * i + l15) * 64 + pcg * 8]);
#pragma unroll
            for (int j = 0; j < 4; ++j)
                bvv[j] = __builtin_bit_cast(bf16x8, *(const ushortx8*)&Bsf[(wc + 16 * j + l15) * 64 + pcg * 8]);
#pragma unroll
            for (int i = 0; i < 4; ++i)
#pragma unroll
                for (int j = 0; j < 4; ++j)
                    acc[i][j] = __builtin_amdgcn_mfma_f32_16x16x32_bf16(av[i], bvv[j], acc[i][j], 0, 0, 0);
        }
        __syncthreads();
    }
    if (PASS == 1) {
#pragma unroll
        for (int i = 0; i < 4; ++i) {
#pragma unroll
            for (int r = 0; r < 4; ++r) {
                int rl = wr + 16 * i + 4 * l4 + r;
                float z2v = z2s[rl];
                float s = 0.f;
#pragma unroll
                for (int j = 0; j < 4; ++j) {
                    int cl = wc + 16 * j + l15;
                    float d2 = z2v + c2s[cl] - 2.0f * acc[i][j][r];
                    float d = sqrtf(fmaxf(d2, 1e-12f));
                    s += __expf(SHIFTC - d);
                }
                s += __shfl_xor(s, 1); s += __shfl_xor(s, 2);
                s += __shfl_xor(s, 4); s += __shfl_xor(s, 8);
                if (l15 == 0) atomicAdd(&Sg[r0 + rl], s);
            }
        }
    } else {
#pragma unroll
        for (int j = 0; j < 4; ++j) {
            int cl = wc + 16 * j + l15;
            float c2v = c2s[cl];
            float cs = 0.f;
#pragma unroll
            for (int i = 0; i < 4; ++i) {
#pragma unroll
                for (int r = 0; r < 4; ++r) {
                    int rl = wr + 16 * i + 4 * l4 + r;
                    float d2 = z2s[rl] + c2v - 2.0f * acc[i][j][r];
                    float d = sqrtf(fmaxf(d2, 1e-12f));
                    cs += __expf(SHIFTC - d) * rs[rl];
                }
            }
            cs += __shfl_xor(cs, 16); cs += __shfl_xor(cs, 32);
            if (l4 == 0) atomicAdd(&cd[c0 + cl], cs);
        }
    }
}

// ---------------- finalize (2-stage, 16 blocks each) ----------------------------
// k_red: cd[k] = sum_s cdp[s][k] (in-place into slice 0); atomicAdd total.
// k_ent: out += sum_k p*log(p+eps)/logK  (out pre-initialized to 1.0 in prep).
__global__ __launch_bounds__(256) void k_red(float* __restrict__ cdp,
                                             float* __restrict__ tot) {
    int k = blockIdx.x * 256 + threadIdx.x;
    float v = 0.f;
#pragma unroll
    for (int s = 0; s < NSLICE; ++s) v += cdp[(size_t)s * NCODES + k];
    cdp[k] = v;
    float t = v;
#pragma unroll
    for (int off = 32; off >= 1; off >>= 1) t += __shfl_down(t, off);
    if ((threadIdx.x & 63) == 0) atomicAdd(tot, t);
}

__global__ __launch_bounds__(256) void k_ent(const float* __restrict__ cdp,
                                             const float* __restrict__ tot,
                                             float* __restrict__ out) {
    int k = blockIdx.x * 256 + threadIdx.x;
    float inv = 1.0f / (tot[0] + 1e-8f);
    float p = cdp[k] * inv;
    float e = p * __logf(p + 1e-8f);
#pragma unroll
    for (int off = 32; off >= 1; off >>= 1) e += __shfl_down(e, off);
    if ((threadIdx.x & 63) == 0)
        atomicAdd(out, e * (1.0f / __logf((float)NCODES)));
}

// ---------------- launcher ----------------
extern "C" void kernel_launch(void* const* d_in, const int* in_sizes, int n_in,
                              void* d_out, int out_size, void* d_ws, size_t ws_size,
                              hipStream_t stream) {
    const float* sf = (const float*)d_in[0];
    const float* cb = (const float*)d_in[1];
    const int* lengths = (const int*)d_in[2];
    const int* stride_p = (const int*)d_in[3];

    float* wsf = (float*)d_ws;
    float* Sg = wsf;                                     // NROWS_PAD
    float* cdp = Sg + NROWS_PAD;                         // NSLICE*NCODES
    float* tot = wsf + NZERO;                            // 1 scalar
    const size_t OFF_Z2 = NZERO2;
    const size_t OFF_C2 = OFF_Z2 + NROWS_PAD;
    const size_t OFF_ZB = (OFF_C2 + NCODES + 3) & ~(size_t)3;  // 16B-align bf16 region
    float* z2 = wsf + OFF_Z2;
    float* c2 = wsf + OFF_C2;
    unsigned short* zbf = (unsigned short*)(wsf + OFF_ZB);     // NROWS_PAD*DIM bf16
    unsigned short* cbbf = zbf + (size_t)NROWS_PAD * DIM;      // NCODES*DIM bf16
    unsigned short* Eg = cbbf + (size_t)NCODES * DIM;          // NROWS_PAD*NCODES bf16

    size_t need = OFF_ZB * 4
                + ((size_t)NROWS_PAD * DIM + (size_t)NCODES * DIM
                 + (size_t)NROWS_PAD * NCODES) * 2;

    k_prep<<<dim3(TBLKS + CBLKS), 256, 0, stream>>>(
        sf, cb, zbf, cbbf, z2, c2, Sg, (float*)d_out);
    if (ws_size >= need) {
        k_gemm1<<<dim3(NBLKX, ROW_TILES), 256, 0, stream>>>(
            zbf, cbbf, z2, c2, lengths, stride_p, Sg, Eg);
        k_scan<<<dim3(2, NROWS_PAD / 64), 256, 0, stream>>>(
            Eg, Sg, lengths, stride_p, cdp);
    } else {
        k_gemm<1><<<dim3(NBLKX, ROW_TILES), 256, 0, stream>>>(zbf, cbbf, z2, c2, lengths, stride_p, Sg, cdp);
        k_gemm<2><<<dim3(NBLKX, ROW_TILES), 256, 0, stream>>>(zbf, cbbf, z2, c2, lengths, stride_p, Sg, cdp);
    }
    k_red<<<dim3(NCODES / 256), 256, 0, stream>>>(cdp, tot);
    k_ent<<<dim3(NCODES / 256), 256, 0, stream>>>(cdp, tot, (float*)d_out);
}